// Round 8
// baseline (475.748 us; speedup 1.0000x reference)
//
#include <hip/hip_runtime.h>
#include <hip/hip_bf16.h>

// ============================================================================
// ConvTemporalGraphical — round 12: round-11 (non-temporal streaming) with
// ext_vector types for the nt builtins (HIP_vector_type uint4/float4 are
// rejected by __builtin_nontemporal_*).
//
//   k0: BtA[80w][288k] = Aeff^T bf16, K regions r=g*3+i, k=r*32+v (padded).
//   k1: MFMA 80-ch 1x1 conv; nt stores for hcn/a1o, nt loads for x.
//   k2a: MFMA Gram: S = U U^T per 32-t chunk -> Spart, no atomics.
//   k2b: 160 blocks (n x 5 w2-groups), shuffle-tree column softmax.
//   k3: MFMA graph contraction, stores sum12[n][t][25v][3ww][16c] (cacheable).
//   k4: MFMA conv3d; nt out stores, nt x loads (h0 prefetched to regs before
//       first barrier -> latency hidden under stage+MFMA).
//
// ws layout (sum12t overlaps Spart — disjoint lifetimes, stream-ordered):
//   a1o 0..13,158,400 | hcn ..80,267,264 | sum12t/Spart 80,267,264..
//   (+39,321,600 / +13,107,200) | BtA 130,598,912 | BtT 130,644,992
//   => total 131,136,512 B.
// ============================================================================

typedef unsigned short u16;
typedef unsigned int   u32;
typedef __attribute__((ext_vector_type(8))) short bf16x8;
typedef __attribute__((ext_vector_type(4))) float f32x4;
typedef __attribute__((ext_vector_type(4))) u32   u32x4;

__device__ __forceinline__ float b2f(u32 u) {
    union { u32 i; float f; } x; x.i = (u & 0xffffu) << 16; return x.f;
}
__device__ __forceinline__ u16 f2b(float f) {
    union { float f; u32 i; } x; x.f = f;
    u32 i = x.i;
    return (u16)((i + 0x7fffu + ((i >> 16) & 1u)) >> 16);   // RNE
}
__device__ __forceinline__ u32 pack2(float a, float b) {
    return (u32)f2b(a) | ((u32)f2b(b) << 16);
}

// ---------------------------------------------------------------------------
// k0: BtA = Aeff^T with (g,i)-region K layout, zero-padded.
// ---------------------------------------------------------------------------
__global__ __launch_bounds__(256) void k0_bta(
    const float* __restrict__ A, const float* __restrict__ PA,
    u16* __restrict__ BtA)
{
    int e = blockIdx.x * 256 + threadIdx.x;
    if (e >= 80 * 288) return;
    int w = e / 288, k = e - w * 288;
    int r = k >> 5, v = k & 31, g = r / 3, i = r - g * 3;
    float val = 0.f;
    if (v < 25 && w < 75) {
        int idx = (g * 75 + i * 25 + v) * 75 + w;
        val = A[idx] + PA[idx];
    }
    BtA[e] = f2b(val);
}

// ---------------------------------------------------------------------------
// k1: MFMA 80-ch 1x1 conv. Block = (n, 32 t's), 256 thr (4 waves), 4 stages.
// ---------------------------------------------------------------------------
__global__ __launch_bounds__(256, 2) void k1_conv80(
    const float* __restrict__ x,
    const float* __restrict__ wa, const float* __restrict__ ba,
    const float* __restrict__ wd, const float* __restrict__ bd,
    const float* __restrict__ wc, const float* __restrict__ bc,
    u16* __restrict__ a1o, u16* __restrict__ hcn)
{
    __shared__ __align__(16) u16 Xt[256 * 64];    // 32,768 B, [col][c] swizzled
    __shared__ __align__(16) u16 Csh[80 * 264];   // 42,240 B, [o][col] stride 264
    char* XtB = (char*)Xt;

    const int b    = blockIdx.x;
    const int n    = b >> 4;
    const int t0   = (b & 15) << 5;               // 32 t's per block
    const int tid  = threadIdx.x;
    const int wave = tid >> 6, lane = tid & 63;
    const int q    = lane >> 4, r = lane & 15;

    // --- per-block preload: W fragments (B-operand layout) + bias ---
    bf16x8 wfrag[5][2];
    float  breg[5];
    #pragma unroll
    for (int mt = 0; mt < 5; ++mt) {
        const int o = mt * 16 + r;
        const float* src = (o < 16) ? (wa + o * 64)
                         : (o < 32) ? (wd + (o - 16) * 64)
                                    : (wc + (o - 32) * 64);
        breg[mt] = (o < 16) ? ba[o] : (o < 32) ? bd[o - 16] : bc[o - 32];
        #pragma unroll
        for (int ks = 0; ks < 2; ++ks) {
            bf16x8 f;
            #pragma unroll
            for (int j = 0; j < 8; ++j)
                f[j] = (short)f2b(src[ks * 32 + q * 8 + j]);
            wfrag[mt][ks] = f;
        }
    }

    // --- a1o t-pad rows (ws is poisoned each launch) ---
    if (t0 == 0) {
        u32x4 z = (u32x4){0u, 0u, 0u, 0u};
        for (int e = tid; e < 50; e += 256)
            __builtin_nontemporal_store(z, (u32x4*)&a1o[((size_t)n * 514) * 400 + e * 8]);
    }
    if (t0 == 480) {
        u32x4 z = (u32x4){0u, 0u, 0u, 0u};
        for (int e = tid; e < 50; e += 256)
            __builtin_nontemporal_store(z, (u32x4*)&a1o[((size_t)n * 514 + 513) * 400 + e * 8]);
    }

    // --- zero Xt pad cols once (v = 25..31 per t; full 128B rows) ---
    {
        u32x4 z = (u32x4){0u, 0u, 0u, 0u};
        for (int e = tid; e < 448; e += 256) {
            const int pc = e >> 3, ch = e & 7;
            const int tl = pc / 7, pv = pc - tl * 7;
            const int col = tl * 32 + 25 + pv;
            *(u32x4*)(XtB + col * 128 + ch * 16) = z;
        }
    }

    auto epilogue = [&](int tbp) {
        for (int e = tid; e < 2048; e += 256) {
            const int cc  = e >> 5;
            const int rem = e & 31;
            const int tl  = rem >> 2, v0 = (rem & 3) << 3;
            const int o   = (cc < 48) ? cc + 32 : cc - 32;
            u32x4 pk = *(const u32x4*)&Csh[o * 264 + tl * 32 + v0];
            __builtin_nontemporal_store(pk,
                (u32x4*)&hcn[(((size_t)n * 64 + cc) * 512 + (tbp + tl)) * 32 + v0]);
        }
        for (int e = tid; e < 400; e += 256) {
            const int tv = e >> 1, h = (e & 1) << 3;
            const int tl = (tv * 41) >> 10;
            const int v  = tv - tl * 25;
            const int cb = tl * 32 + v;
            u16 a[8];
            #pragma unroll
            for (int k = 0; k < 8; ++k) a[k] = Csh[(h + k) * 264 + cb];
            u32x4 pk;
            pk.x = (u32)a[0] | ((u32)a[1] << 16);
            pk.y = (u32)a[2] | ((u32)a[3] << 16);
            pk.z = (u32)a[4] | ((u32)a[5] << 16);
            pk.w = (u32)a[6] | ((u32)a[7] << 16);
            __builtin_nontemporal_store(pk,
                (u32x4*)&a1o[(((size_t)n * 514 + (tbp + tl + 1)) * 25 + v) * 16 + h]);
        }
    };

    for (int s = 0; s < 4; ++s) {
        const int tb = t0 + s * 8;

        if (s > 0) epilogue(tb - 8);
        for (int e = tid; e < 400; e += 256) {
            const int co = e / 50;
            const int tq = e - co * 50;
            const float* gp = x + (((size_t)n * 64 + co * 8) * 512 + tb) * 25 + tq * 4;
            float fl[32];
            #pragma unroll
            for (int i = 0; i < 8; ++i) {
                const f32x4 t4 = __builtin_nontemporal_load(
                    (const f32x4*)(gp + (size_t)i * 12800));
                fl[i * 4 + 0] = t4.x; fl[i * 4 + 1] = t4.y;
                fl[i * 4 + 2] = t4.z; fl[i * 4 + 3] = t4.w;
            }
            #pragma unroll
            for (int j = 0; j < 4; ++j) {
                const int tv  = tq * 4 + j;
                const int tl  = (tv * 41) >> 10;
                const int col = tl * 32 + (tv - tl * 25);
                u32x4 pk;
                pk.x = pack2(fl[0 * 4 + j], fl[1 * 4 + j]);
                pk.y = pack2(fl[2 * 4 + j], fl[3 * 4 + j]);
                pk.z = pack2(fl[4 * 4 + j], fl[5 * 4 + j]);
                pk.w = pack2(fl[6 * 4 + j], fl[7 * 4 + j]);
                *(u32x4*)(XtB + col * 128 + ((co * 16) ^ ((col & 7) << 4))) = pk;
            }
        }
        __syncthreads();

        {
            f32x4 acc[4][5];
            #pragma unroll
            for (int a_ = 0; a_ < 4; ++a_)
                #pragma unroll
                for (int m_ = 0; m_ < 5; ++m_)
                    acc[a_][m_] = (f32x4){0.f, 0.f, 0.f, 0.f};

            #pragma unroll
            for (int nt4 = 0; nt4 < 4; ++nt4) {
                const int col = (wave * 4 + nt4) * 16 + r;
                const int swz = (col & 7) << 4;
                const char* rowp = (const char*)Xt + col * 128;
                const bf16x8 x0 = *(const bf16x8*)(rowp + ((q * 16) ^ swz));
                const bf16x8 x1 = *(const bf16x8*)(rowp + ((64 + q * 16) ^ swz));
                #pragma unroll
                for (int mt = 0; mt < 5; ++mt) {
                    acc[nt4][mt] = __builtin_amdgcn_mfma_f32_16x16x32_bf16(
                        x0, wfrag[mt][0], acc[nt4][mt], 0, 0, 0);
                    acc[nt4][mt] = __builtin_amdgcn_mfma_f32_16x16x32_bf16(
                        x1, wfrag[mt][1], acc[nt4][mt], 0, 0, 0);
                }
            }
            #pragma unroll
            for (int nt4 = 0; nt4 < 4; ++nt4) {
                const int colb = (wave * 4 + nt4) * 16 + q * 4;
                #pragma unroll
                for (int mt = 0; mt < 5; ++mt) {
                    const int o = mt * 16 + r;
                    const float bi = breg[mt];
                    uint2 pr;
                    pr.x = pack2(acc[nt4][mt][0] + bi, acc[nt4][mt][1] + bi);
                    pr.y = pack2(acc[nt4][mt][2] + bi, acc[nt4][mt][3] + bi);
                    *(uint2*)&Csh[o * 264 + colb] = pr;
                }
            }
        }
        __syncthreads();
    }
    epilogue(t0 + 24);
}

// ---------------------------------------------------------------------------
// k2a: MFMA Gram matrix. Block = (n, 32-t chunk), 4 waves split k.
// ---------------------------------------------------------------------------
__global__ __launch_bounds__(256, 2) void k2a_mfma(
    const u16* __restrict__ a1o, float* __restrict__ Spart)
{
    __shared__ u16 U[80 * 136];        // 21,760 B (stride 136: 2-way banks)
    __shared__ float Sred[80 * 80];    // 25,600 B
    const int b   = blockIdx.x;
    const int n   = b >> 4;
    const int tc  = b & 15;
    const int t0  = tc * 32;
    const int tid = threadIdx.x;
    const int wave = tid >> 6, lane = tid & 63;
    const int q = lane >> 4, col = lane & 15;

    f32x4 acc[25];
    #pragma unroll
    for (int i = 0; i < 25; ++i) acc[i] = (f32x4){0.f, 0.f, 0.f, 0.f};

    for (int s = 0; s < 4; ++s) {
        __syncthreads();                               // prior reads done
        for (int e = tid; e < 1280; e += 256) {        // stage 8 t's
            int row = e >> 4, c8 = (e & 15) << 3;
            u32x4 val = (u32x4){0u, 0u, 0u, 0u};
            if (row < 75) {
                int i = row / 25, v = row - i * 25;
                int tl = c8 >> 4, o0 = c8 & 8;
                int tp = t0 + s * 8 + tl + i;          // padded t idx, 0..513
                val = *(const u32x4*)&a1o[(((size_t)n * 514 + tp) * 25 + v) * 16 + o0];
            }
            *(u32x4*)&U[row * 136 + c8] = val;
        }
        __syncthreads();

        const int k0 = wave * 32 + q * 8;
        bf16x8 fr[5];
        #pragma unroll
        for (int r = 0; r < 5; ++r)
            fr[r] = *(const bf16x8*)&U[(r * 16 + col) * 136 + k0];
        #pragma unroll
        for (int mt = 0; mt < 5; ++mt)
            #pragma unroll
            for (int nt = 0; nt < 5; ++nt)
                acc[mt * 5 + nt] = __builtin_amdgcn_mfma_f32_16x16x32_bf16(
                    fr[mt], fr[nt], acc[mt * 5 + nt], 0, 0, 0);
    }

    for (int w = 0; w < 4; ++w) {
        if (wave == w) {
            #pragma unroll
            for (int mt = 0; mt < 5; ++mt)
                #pragma unroll
                for (int nt = 0; nt < 5; ++nt)
                    #pragma unroll
                    for (int reg = 0; reg < 4; ++reg) {
                        int idx = (mt * 16 + q * 4 + reg) * 80 + nt * 16 + col;
                        if (w == 0) Sred[idx]  = acc[mt * 5 + nt][reg];
                        else        Sred[idx] += acc[mt * 5 + nt][reg];
                    }
        }
        __syncthreads();
    }
    float* dst = &Spart[(size_t)(n * 16 + tc) * 6400];
    for (int e = tid; e < 6400; e += 256) dst[e] = Sred[e];
}

// ---------------------------------------------------------------------------
// k2b: grid = (32 n x 5 w2-groups). Sum 16 partials, /75, column softmax
// over w1 with 16-lane shuffle trees; write BtT[n][80][96] = att^T.
// ---------------------------------------------------------------------------
__global__ __launch_bounds__(256) void k2b_softmax(
    const float* __restrict__ Spart, u16* __restrict__ BtT)
{
    __shared__ float S2[75][17];                  // [w1][w2l], pad to 17
    const int b = blockIdx.x;
    const int n = b / 5, w2g = b - n * 5;
    const int w2base = w2g * 16;
    const int tid = threadIdx.x;

    // phase 1: ks-reduction, 1200 elems
    for (int e = tid; e < 1200; e += 256) {
        const int w1 = e >> 4, w2l = e & 15;
        const float* sp = &Spart[(size_t)(n * 16) * 6400 + w1 * 80 + w2base + w2l];
        float s = 0.f;
        #pragma unroll
        for (int ks = 0; ks < 16; ++ks) s += sp[(size_t)ks * 6400];
        S2[w1][w2l] = s * (1.0f / 75.0f);
    }
    __syncthreads();

    // phase 2: softmax over w1, 16 lanes per column (cols are lane-contiguous)
    const int w2l = tid >> 4, j = tid & 15;
    float m = -1e30f;
    for (int w1 = j; w1 < 75; w1 += 16) m = fmaxf(m, S2[w1][w2l]);
    #pragma unroll
    for (int off = 8; off; off >>= 1) m = fmaxf(m, __shfl_xor(m, off, 16));
    float s = 0.f;
    for (int w1 = j; w1 < 75; w1 += 16) {
        const float e = __expf(S2[w1][w2l] - m);
        S2[w1][w2l] = e;
        s += e;
    }
    #pragma unroll
    for (int off = 8; off; off >>= 1) s += __shfl_xor(s, off, 16);
    const float r = 1.0f / s;
    for (int w1 = j; w1 < 75; w1 += 16) S2[w1][w2l] *= r;
    __syncthreads();

    // phase 3: store BtT rows w2base..w2base+15 (w2>=75 or v>=25 -> 0)
    for (int e = tid; e < 1536; e += 256) {
        const int wl = e / 96, k = e - wl * 96;
        const int i = k >> 5, v = k & 31;
        const int w2 = w2base + wl;
        const float val = (w2 < 75 && v < 25) ? S2[i * 25 + v][wl] : 0.f;
        BtT[((size_t)n * 80 + w2) * 96 + k] = f2b(val);
    }
}

// ---------------------------------------------------------------------------
// k3: MFMA graph contraction, operand-swapped: D[w][c] (row=w, col=c).
// Stores sum12[n][t][25v][3ww][16c] — 16-lane 32B segments, c innermost.
// ---------------------------------------------------------------------------
__global__ __launch_bounds__(256, 2) void k3_graph(
    const u16* __restrict__ hcn, const u16* __restrict__ BtA,
    const u16* __restrict__ BtT, u16* __restrict__ sum12)
{
    __shared__ u16 Bt[80 * 392];   // row stride 392 u16 = 784 B (2-way banks)
    const int b    = blockIdx.x;
    const int n    = b >> 4;
    const int tblk = (b & 15) << 5;
    const int tid  = threadIdx.x;

    for (int e = tid; e < 3840; e += 256) {             // stage Bt (uint4)
        int row = e / 48, cs = e - row * 48;
        u32x4 val;
        if (cs < 36) val = *(const u32x4*)&BtA[row * 288 + cs * 8];
        else         val = *(const u32x4*)&BtT[((size_t)n * 80 + row) * 96 + (cs - 36) * 8];
        *(u32x4*)&Bt[row * 392 + cs * 8] = val;
    }
    __syncthreads();

    const int wave = tid >> 6, lane = tid & 63;
    const int c = lane & 15, q = lane >> 4;
    const int tb = tblk + wave * 8;

    for (int tt = 0; tt < 8; tt += 2) {
        const int t0 = tb + tt, t1 = t0 + 1;
        bf16x8 a0[12], a1[12];
        #pragma unroll
        for (int r = 0; r < 12; ++r) {
            const int g = r / 3, i = r - g * 3;
            const size_t rowb = ((size_t)n * 64 + g * 16 + c) * 512;
            const int tp0 = t0 + i - 1, tp1 = t1 + i - 1;
            a0[r] = (tp0 >= 0 && tp0 < 512)
                  ? *(const bf16x8*)&hcn[(rowb + tp0) * 32 + q * 8] : (bf16x8)(short)0;
            a1[r] = (tp1 >= 0 && tp1 < 512)
                  ? *(const bf16x8*)&hcn[(rowb + tp1) * 32 + q * 8] : (bf16x8)(short)0;
        }
        #pragma unroll 1
        for (int nt = 0; nt < 5; ++nt) {
            f32x4 acc0 = {0.f, 0.f, 0.f, 0.f};
            f32x4 acc1 = {0.f, 0.f, 0.f, 0.f};
            const u16* bp = &Bt[(nt * 16 + c) * 392 + q * 8];
            #pragma unroll
            for (int r = 0; r < 12; ++r) {
                bf16x8 bf = *(const bf16x8*)(bp + r * 32);
                // swapped: A = Bt rows (w), B = hcn cols (c) -> D[w][c]
                acc0 = __builtin_amdgcn_mfma_f32_16x16x32_bf16(bf, a0[r], acc0, 0, 0, 0);
                acc1 = __builtin_amdgcn_mfma_f32_16x16x32_bf16(bf, a1[r], acc1, 0, 0, 0);
            }
            // D: row = q*4+reg = w, col = lane&15 = c
            const size_t tb0 = ((size_t)n * 512 + t0) * 1200;
            const size_t tb1 = ((size_t)n * 512 + t1) * 1200;
            #pragma unroll
            for (int reg = 0; reg < 4; ++reg) {
                const int w = nt * 16 + q * 4 + reg;
                if (w < 75) {
                    const int ww = (w >= 50) ? 2 : ((w >= 25) ? 1 : 0);
                    const int v  = w - ww * 25;
                    const int off = (v * 3 + ww) * 16 + c;
                    sum12[tb0 + off] = f2b(acc0[reg]);
                    sum12[tb1 + off] = f2b(acc1[reg]);
                }
            }
        }
    }
}

// ---------------------------------------------------------------------------
// k4: MFMA conv3d(1,3,1) + bias + BN + residual + relu.
// Block = (n, 8 t's), LDS = 32,768 B union -> 5 blocks/CU. Epilogue in two
// o-halves; nt out stores; nt x loads with h0 register prefetch.
// ---------------------------------------------------------------------------
__global__ __launch_bounds__(256, 5) void k4_out(
    const u16* __restrict__ sum12,
    const float* __restrict__ ow, const float* __restrict__ obias,
    const float* __restrict__ bg, const float* __restrict__ bb,
    const float* __restrict__ bm, const float* __restrict__ bv,
    const float* __restrict__ x, float* __restrict__ out)
{
    __shared__ __align__(16) char smem[32768];          // exact 32 KB union
    float* Csh  = (float*)smem;                         // [32 o'][204] per half
    char*  BshB = smem;                                 // [256 col][64 k] swz

    const int i    = blockIdx.x;
    const int b    = (i & 7) * 256 + (i >> 3);          // XCD-grouped relabel
    const int n    = b >> 6;
    const int t0   = (b & 63) << 3;
    const int tid  = threadIdx.x;
    const int wave = tid >> 6, lane = tid & 63;
    const int q    = lane >> 4, c15 = lane & 15;

    // zero pad chunks: kpad (j=6,7 all 256 cols) + vpad cols (56 x 8 chunks)
    {
        u32x4 z = (u32x4){0u, 0u, 0u, 0u};
        for (int e = tid; e < 960; e += 256) {
            int col, j;
            if (e < 512) { col = e >> 1; j = 6 + (e & 1); }
            else {
                const int r2 = e - 512;
                const int cc = r2 >> 3; j = r2 & 7;
                const int tl = cc / 7, pv = cc - tl * 7;
                col = tl * 32 + 25 + pv;
            }
            *(u32x4*)(BshB + col * 128 + ((j * 16) ^ ((col & 7) << 4))) = z;
        }
    }
    // stage valid rows (8 t, v<25): 6 uint4 per (t,v); contiguous 96B rows.
    for (int e = tid; e < 1200; e += 256) {
        const int j  = e % 6;
        const int rv = e / 6;                     // tl*25 + v, < 200
        const int tl = (rv * 41) >> 10;
        const int v  = rv - tl * 25;
        const u32x4 val = *(const u32x4*)
            &sum12[((size_t)n * 512 + t0 + tl) * 1200 + v * 48 + j * 8];
        const int col = tl * 32 + v;
        *(u32x4*)(BshB + col * 128 + ((j * 16) ^ ((col & 7) << 4))) = val;
    }

    // W2 A-fragments: A[o][k], k = ww*16+c (48 real, pad to 64 with zeros).
    bf16x8 wfrag[4][2];
    #pragma unroll
    for (int mt = 0; mt < 4; ++mt) {
        const int o = mt * 16 + c15;
        #pragma unroll
        for (int ks = 0; ks < 2; ++ks) {
            bf16x8 f;
            #pragma unroll
            for (int j = 0; j < 8; ++j) {
                const int k = ks * 32 + q * 8 + j;
                const int cc = k & 15, ww = k >> 4;
                f[j] = (k < 48) ? (short)f2b(ow[o * 48 + cc * 3 + ww]) : (short)0;
            }
            wfrag[mt][ks] = f;
        }
    }
    // BN/bias folded: y_pre = acc*scl + shf2, shf2 = (bias - mean)*scl + beta.
    float scl[4][4], shf2[4][4];
    #pragma unroll
    for (int mt = 0; mt < 4; ++mt)
        #pragma unroll
        for (int reg = 0; reg < 4; ++reg) {
            const int o = mt * 16 + q * 4 + reg;
            const float s = bg[o] * rsqrtf(bv[o] + 1e-5f);
            scl[mt][reg]  = s;
            shf2[mt][reg] = bb[o] + (obias[o] - bm[o]) * s;
        }

    // prefetch h0 x-residual (o = 0..31) into regs: issue BEFORE the first
    // barrier so HBM latency hides under stage-wait + MFMA phase.
    f32x4 xp[7];
    #pragma unroll
    for (int j = 0; j < 7; ++j) {
        const int e = tid + j * 256;
        if (e < 1600) {
            const int op = e / 50, jj = e - op * 50;
            xp[j] = __builtin_nontemporal_load((const f32x4*)
                &x[(((size_t)n * 64 + op) * 512 + t0) * 25 + jj * 4]);
        }
    }
    __syncthreads();

    f32x4 acc[4][4];
    #pragma unroll
    for (int ct = 0; ct < 4; ++ct)
        #pragma unroll
        for (int mt = 0; mt < 4; ++mt)
            acc[ct][mt] = (f32x4){0.f, 0.f, 0.f, 0.f};

    const int wb = wave * 64;
    #pragma unroll
    for (int ct = 0; ct < 4; ++ct) {
        const int col = wb + ct * 16 + c15;
        const int swz = (col & 7) << 4;
        const char* rp = BshB + col * 128;
        const bf16x8 b0 = *(const bf16x8*)(rp + ((q * 16) ^ swz));
        const bf16x8 b1 = *(const bf16x8*)(rp + ((64 + q * 16) ^ swz));
        #pragma unroll
        for (int mt = 0; mt < 4; ++mt) {
            acc[ct][mt] = __builtin_amdgcn_mfma_f32_16x16x32_bf16(
                wfrag[mt][0], b0, acc[ct][mt], 0, 0, 0);
            acc[ct][mt] = __builtin_amdgcn_mfma_f32_16x16x32_bf16(
                wfrag[mt][1], b1, acc[ct][mt], 0, 0, 0);
        }
    }
    __syncthreads();                              // Bsh reads done

    // ---- half 0: o in [0,32) ----
    #pragma unroll
    for (int ct = 0; ct < 4; ++ct) {
        const int col = wb + ct * 16 + c15;
        const int tl = col >> 5, v = col & 31;
        if (v < 25) {
            const int cc = tl * 25 + v;
            #pragma unroll
            for (int mi = 0; mi < 2; ++mi) {
                #pragma unroll
                for (int reg = 0; reg < 4; ++reg) {
                    const int op = mi * 16 + q * 4 + reg;
                    Csh[op * 204 + cc] =
                        acc[ct][mi][reg] * scl[mi][reg] + shf2[mi][reg];
                }
            }
        }
    }
    __syncthreads();

    #pragma unroll
    for (int j = 0; j < 7; ++j) {
        const int e = tid + j * 256;
        if (e < 1600) {
            const int op = e / 50, jj = e - op * 50;
            const size_t gidx = (((size_t)n * 64 + op) * 512 + t0) * 25 + jj * 4;
            const float* cp = &Csh[op * 204 + jj * 4];
            f32x4 yv;
            yv.x = fmaxf(cp[0] + xp[j].x, 0.f);
            yv.y = fmaxf(cp[1] + xp[j].y, 0.f);
            yv.z = fmaxf(cp[2] + xp[j].z, 0.f);
            yv.w = fmaxf(cp[3] + xp[j].w, 0.f);
            __builtin_nontemporal_store(yv, (f32x4*)&out[gidx]);
        }
    }
    __syncthreads();

    // ---- half 1: o in [32,64) ----
    #pragma unroll
    for (int ct = 0; ct < 4; ++ct) {
        const int col = wb + ct * 16 + c15;
        const int tl = col >> 5, v = col & 31;
        if (v < 25) {
            const int cc = tl * 25 + v;
            #pragma unroll
            for (int mi = 0; mi < 2; ++mi) {
                const int mt = 2 + mi;
                #pragma unroll
                for (int reg = 0; reg < 4; ++reg) {
                    const int op = mi * 16 + q * 4 + reg;
                    Csh[op * 204 + cc] =
                        acc[ct][mt][reg] * scl[mt][reg] + shf2[mt][reg];
                }
            }
        }
    }
    __syncthreads();

    for (int e = tid; e < 1600; e += 256) {
        const int op = e / 50, jj = e - op * 50;
        const int o  = 32 + op;
        const size_t gidx = (((size_t)n * 64 + o) * 512 + t0) * 25 + jj * 4;
        const f32x4 xv = __builtin_nontemporal_load((const f32x4*)&x[gidx]);
        const float* cp = &Csh[op * 204 + jj * 4];
        f32x4 yv;
        yv.x = fmaxf(cp[0] + xv.x, 0.f);
        yv.y = fmaxf(cp[1] + xv.y, 0.f);
        yv.z = fmaxf(cp[2] + xv.z, 0.f);
        yv.w = fmaxf(cp[3] + xv.w, 0.f);
        __builtin_nontemporal_store(yv, (f32x4*)&out[gidx]);
    }
}

// ---------------------------------------------------------------------------
extern "C" void kernel_launch(void* const* d_in, const int* in_sizes, int n_in,
                              void* d_out, int out_size, void* d_ws, size_t ws_size,
                              hipStream_t stream)
{
    const float* x  = (const float*)d_in[0];
    const float* A  = (const float*)d_in[1];
    const float* PA = (const float*)d_in[2];
    const float* wa = (const float*)d_in[3];
    const float* ba = (const float*)d_in[4];
    const float* wd = (const float*)d_in[5];
    const float* bd = (const float*)d_in[6];
    const float* wc = (const float*)d_in[7];
    const float* bc = (const float*)d_in[8];
    const float* ow = (const float*)d_in[9];
    const float* ob = (const float*)d_in[10];
    const float* bg = (const float*)d_in[11];
    const float* bb = (const float*)d_in[12];
    const float* bm = (const float*)d_in[13];
    const float* bv = (const float*)d_in[14];
    float* out = (float*)d_out;

    char* ws = (char*)d_ws;
    u16*   a1o   = (u16*)(ws);                           // 13,158,400 B
    u16*   hcn   = (u16*)(ws + 13158400);                // 67,108,864 B
    u16*   sum12 = (u16*)(ws + 80267264);                // 39,321,600 B (k3->k4)
    float* Spart = (float*)(ws + 80267264);              // 13,107,200 B (k2a->k2b)
    u16*   BtA   = (u16*)(ws + 130598912);               // 46,080 B
    u16*   BtT   = (u16*)(ws + 130644992);               // 491,520 B
    // total 131,136,512 B (sum12 overlaps Spart: disjoint lifetimes)

    k0_bta    <<<90,   256, 0, stream>>>(A, PA, BtA);
    k1_conv80 <<<512,  256, 0, stream>>>(x, wa, ba, wd, bd, wc, bc, a1o, hcn);
    k2a_mfma  <<<512,  256, 0, stream>>>(a1o, Spart);
    k2b_softmax<<<160, 256, 0, stream>>>(Spart, BtT);
    k3_graph  <<<512,  256, 0, stream>>>(hcn, BtA, BtT, sum12);
    k4_out    <<<2048, 256, 0, stream>>>(sum12, ow, ob, bg, bb, bm, bv, x, out);
}

// Round 9
// 415.401 us; speedup vs baseline: 1.1453x; 1.1453x over previous
//
#include <hip/hip_runtime.h>
#include <hip/hip_bf16.h>

// ============================================================================
// ConvTemporalGraphical — round 13: best-measured assembly.
//   k4 = round-7 version verbatim (3 blk/CU, 52KB LDS union, single-pass
//        epilogue, 800B store regions, no XCD relabel, no non-temporal):
//        measured 108 µs / WRITE 102 MB / FETCH 77 MB.
//   k2b = round-8 160-block shuffle softmax (confirmed ~25-30 µs win).
//   All non-temporal accesses reverted (r12: nt = +145 MB WRITE, +70 MB FETCH
//        — L2 write-combining was doing useful work).
//
//   k0: BtA[80w][288k] = Aeff^T bf16, K regions r=g*3+i, k=r*32+v (padded).
//   k1: MFMA 80-ch 1x1 conv (round-5 structure).
//   k2a: MFMA Gram: S = U U^T per 32-t chunk -> Spart, no atomics.
//   k2b: 160 blocks (n x 5 w2-groups), shuffle-tree column softmax.
//   k3: MFMA graph contraction, operand-swapped store sum12[n][t][25v][3ww][16c].
//   k4: MFMA conv3d + bias + BN + residual + relu (round-7 config).
//
// ws layout (sum12t overlaps Spart — disjoint lifetimes, stream-ordered):
//   a1o 0..13,158,400 | hcn ..80,267,264 | sum12t/Spart 80,267,264..
//   (+39,321,600 / +13,107,200) | BtA 130,598,912 | BtT 130,644,992
//   => total 131,136,512 B.
// ============================================================================

typedef unsigned short u16;
typedef unsigned int   u32;
typedef __attribute__((ext_vector_type(8))) short bf16x8;
typedef __attribute__((ext_vector_type(4))) float f32x4;

__device__ __forceinline__ float b2f(u32 u) {
    union { u32 i; float f; } x; x.i = (u & 0xffffu) << 16; return x.f;
}
__device__ __forceinline__ u16 f2b(float f) {
    union { float f; u32 i; } x; x.f = f;
    u32 i = x.i;
    return (u16)((i + 0x7fffu + ((i >> 16) & 1u)) >> 16);   // RNE
}
__device__ __forceinline__ u32 pack2(float a, float b) {
    return (u32)f2b(a) | ((u32)f2b(b) << 16);
}

// ---------------------------------------------------------------------------
// k0: BtA = Aeff^T with (g,i)-region K layout, zero-padded.
// ---------------------------------------------------------------------------
__global__ __launch_bounds__(256) void k0_bta(
    const float* __restrict__ A, const float* __restrict__ PA,
    u16* __restrict__ BtA)
{
    int e = blockIdx.x * 256 + threadIdx.x;
    if (e >= 80 * 288) return;
    int w = e / 288, k = e - w * 288;
    int r = k >> 5, v = k & 31, g = r / 3, i = r - g * 3;
    float val = 0.f;
    if (v < 25 && w < 75) {
        int idx = (g * 75 + i * 25 + v) * 75 + w;
        val = A[idx] + PA[idx];
    }
    BtA[e] = f2b(val);
}

// ---------------------------------------------------------------------------
// k1: MFMA 80-ch 1x1 conv. Block = (n, 32 t's), 256 thr (4 waves), 4 stages.
// ---------------------------------------------------------------------------
__global__ __launch_bounds__(256, 2) void k1_conv80(
    const float* __restrict__ x,
    const float* __restrict__ wa, const float* __restrict__ ba,
    const float* __restrict__ wd, const float* __restrict__ bd,
    const float* __restrict__ wc, const float* __restrict__ bc,
    u16* __restrict__ a1o, u16* __restrict__ hcn)
{
    __shared__ __align__(16) u16 Xt[256 * 64];    // 32,768 B, [col][c] swizzled
    __shared__ __align__(16) u16 Csh[80 * 264];   // 42,240 B, [o][col] stride 264
    char* XtB = (char*)Xt;

    const int b    = blockIdx.x;
    const int n    = b >> 4;
    const int t0   = (b & 15) << 5;               // 32 t's per block
    const int tid  = threadIdx.x;
    const int wave = tid >> 6, lane = tid & 63;
    const int q    = lane >> 4, r = lane & 15;

    // --- per-block preload: W fragments (B-operand layout) + bias ---
    bf16x8 wfrag[5][2];
    float  breg[5];
    #pragma unroll
    for (int mt = 0; mt < 5; ++mt) {
        const int o = mt * 16 + r;
        const float* src = (o < 16) ? (wa + o * 64)
                         : (o < 32) ? (wd + (o - 16) * 64)
                                    : (wc + (o - 32) * 64);
        breg[mt] = (o < 16) ? ba[o] : (o < 32) ? bd[o - 16] : bc[o - 32];
        #pragma unroll
        for (int ks = 0; ks < 2; ++ks) {
            bf16x8 f;
            #pragma unroll
            for (int j = 0; j < 8; ++j)
                f[j] = (short)f2b(src[ks * 32 + q * 8 + j]);
            wfrag[mt][ks] = f;
        }
    }

    // --- a1o t-pad rows (ws is poisoned each launch) ---
    if (t0 == 0) {
        uint4 z; z.x = 0u; z.y = 0u; z.z = 0u; z.w = 0u;
        for (int e = tid; e < 50; e += 256)
            *(uint4*)&a1o[((size_t)n * 514) * 400 + e * 8] = z;
    }
    if (t0 == 480) {
        uint4 z; z.x = 0u; z.y = 0u; z.z = 0u; z.w = 0u;
        for (int e = tid; e < 50; e += 256)
            *(uint4*)&a1o[((size_t)n * 514 + 513) * 400 + e * 8] = z;
    }

    // --- zero Xt pad cols once (v = 25..31 per t; full 128B rows) ---
    {
        uint4 z; z.x = 0u; z.y = 0u; z.z = 0u; z.w = 0u;
        for (int e = tid; e < 448; e += 256) {
            const int pc = e >> 3, ch = e & 7;
            const int tl = pc / 7, pv = pc - tl * 7;
            const int col = tl * 32 + 25 + pv;
            *(uint4*)(XtB + col * 128 + ch * 16) = z;
        }
    }

    auto epilogue = [&](int tbp) {
        for (int e = tid; e < 2048; e += 256) {
            const int cc  = e >> 5;
            const int rem = e & 31;
            const int tl  = rem >> 2, v0 = (rem & 3) << 3;
            const int o   = (cc < 48) ? cc + 32 : cc - 32;
            uint4 pk = *(const uint4*)&Csh[o * 264 + tl * 32 + v0];
            *(uint4*)&hcn[(((size_t)n * 64 + cc) * 512 + (tbp + tl)) * 32 + v0] = pk;
        }
        for (int e = tid; e < 400; e += 256) {
            const int tv = e >> 1, h = (e & 1) << 3;
            const int tl = (tv * 41) >> 10;
            const int v  = tv - tl * 25;
            const int cb = tl * 32 + v;
            u16 a[8];
            #pragma unroll
            for (int k = 0; k < 8; ++k) a[k] = Csh[(h + k) * 264 + cb];
            uint4 pk;
            pk.x = (u32)a[0] | ((u32)a[1] << 16);
            pk.y = (u32)a[2] | ((u32)a[3] << 16);
            pk.z = (u32)a[4] | ((u32)a[5] << 16);
            pk.w = (u32)a[6] | ((u32)a[7] << 16);
            *(uint4*)&a1o[(((size_t)n * 514 + (tbp + tl + 1)) * 25 + v) * 16 + h] = pk;
        }
    };

    for (int s = 0; s < 4; ++s) {
        const int tb = t0 + s * 8;

        if (s > 0) epilogue(tb - 8);
        for (int e = tid; e < 400; e += 256) {
            const int co = e / 50;
            const int tq = e - co * 50;
            const float* gp = x + (((size_t)n * 64 + co * 8) * 512 + tb) * 25 + tq * 4;
            float fl[32];
            #pragma unroll
            for (int i = 0; i < 8; ++i) {
                const float4 t4 = *(const float4*)(gp + (size_t)i * 12800);
                fl[i * 4 + 0] = t4.x; fl[i * 4 + 1] = t4.y;
                fl[i * 4 + 2] = t4.z; fl[i * 4 + 3] = t4.w;
            }
            #pragma unroll
            for (int j = 0; j < 4; ++j) {
                const int tv  = tq * 4 + j;
                const int tl  = (tv * 41) >> 10;
                const int col = tl * 32 + (tv - tl * 25);
                uint4 pk;
                pk.x = pack2(fl[0 * 4 + j], fl[1 * 4 + j]);
                pk.y = pack2(fl[2 * 4 + j], fl[3 * 4 + j]);
                pk.z = pack2(fl[4 * 4 + j], fl[5 * 4 + j]);
                pk.w = pack2(fl[6 * 4 + j], fl[7 * 4 + j]);
                *(uint4*)(XtB + col * 128 + ((co * 16) ^ ((col & 7) << 4))) = pk;
            }
        }
        __syncthreads();

        {
            f32x4 acc[4][5];
            #pragma unroll
            for (int a_ = 0; a_ < 4; ++a_)
                #pragma unroll
                for (int m_ = 0; m_ < 5; ++m_)
                    acc[a_][m_] = (f32x4){0.f, 0.f, 0.f, 0.f};

            #pragma unroll
            for (int nt4 = 0; nt4 < 4; ++nt4) {
                const int col = (wave * 4 + nt4) * 16 + r;
                const int swz = (col & 7) << 4;
                const char* rowp = (const char*)Xt + col * 128;
                const bf16x8 x0 = *(const bf16x8*)(rowp + ((q * 16) ^ swz));
                const bf16x8 x1 = *(const bf16x8*)(rowp + ((64 + q * 16) ^ swz));
                #pragma unroll
                for (int mt = 0; mt < 5; ++mt) {
                    acc[nt4][mt] = __builtin_amdgcn_mfma_f32_16x16x32_bf16(
                        x0, wfrag[mt][0], acc[nt4][mt], 0, 0, 0);
                    acc[nt4][mt] = __builtin_amdgcn_mfma_f32_16x16x32_bf16(
                        x1, wfrag[mt][1], acc[nt4][mt], 0, 0, 0);
                }
            }
            #pragma unroll
            for (int nt4 = 0; nt4 < 4; ++nt4) {
                const int colb = (wave * 4 + nt4) * 16 + q * 4;
                #pragma unroll
                for (int mt = 0; mt < 5; ++mt) {
                    const int o = mt * 16 + r;
                    const float bi = breg[mt];
                    uint2 pr;
                    pr.x = pack2(acc[nt4][mt][0] + bi, acc[nt4][mt][1] + bi);
                    pr.y = pack2(acc[nt4][mt][2] + bi, acc[nt4][mt][3] + bi);
                    *(uint2*)&Csh[o * 264 + colb] = pr;
                }
            }
        }
        __syncthreads();
    }
    epilogue(t0 + 24);
}

// ---------------------------------------------------------------------------
// k2a: MFMA Gram matrix. Block = (n, 32-t chunk), 4 waves split k.
// ---------------------------------------------------------------------------
__global__ __launch_bounds__(256, 2) void k2a_mfma(
    const u16* __restrict__ a1o, float* __restrict__ Spart)
{
    __shared__ u16 U[80 * 136];        // 21,760 B (stride 136: 2-way banks)
    __shared__ float Sred[80 * 80];    // 25,600 B
    const int b   = blockIdx.x;
    const int n   = b >> 4;
    const int tc  = b & 15;
    const int t0  = tc * 32;
    const int tid = threadIdx.x;
    const int wave = tid >> 6, lane = tid & 63;
    const int q = lane >> 4, col = lane & 15;

    f32x4 acc[25];
    #pragma unroll
    for (int i = 0; i < 25; ++i) acc[i] = (f32x4){0.f, 0.f, 0.f, 0.f};

    for (int s = 0; s < 4; ++s) {
        __syncthreads();                               // prior reads done
        for (int e = tid; e < 1280; e += 256) {        // stage 8 t's
            int row = e >> 4, c8 = (e & 15) << 3;
            uint4 val; val.x = 0u; val.y = 0u; val.z = 0u; val.w = 0u;
            if (row < 75) {
                int i = row / 25, v = row - i * 25;
                int tl = c8 >> 4, o0 = c8 & 8;
                int tp = t0 + s * 8 + tl + i;          // padded t idx, 0..513
                val = *(const uint4*)&a1o[(((size_t)n * 514 + tp) * 25 + v) * 16 + o0];
            }
            *(uint4*)&U[row * 136 + c8] = val;
        }
        __syncthreads();

        const int k0 = wave * 32 + q * 8;
        bf16x8 fr[5];
        #pragma unroll
        for (int r = 0; r < 5; ++r)
            fr[r] = *(const bf16x8*)&U[(r * 16 + col) * 136 + k0];
        #pragma unroll
        for (int mt = 0; mt < 5; ++mt)
            #pragma unroll
            for (int nt = 0; nt < 5; ++nt)
                acc[mt * 5 + nt] = __builtin_amdgcn_mfma_f32_16x16x32_bf16(
                    fr[mt], fr[nt], acc[mt * 5 + nt], 0, 0, 0);
    }

    for (int w = 0; w < 4; ++w) {
        if (wave == w) {
            #pragma unroll
            for (int mt = 0; mt < 5; ++mt)
                #pragma unroll
                for (int nt = 0; nt < 5; ++nt)
                    #pragma unroll
                    for (int reg = 0; reg < 4; ++reg) {
                        int idx = (mt * 16 + q * 4 + reg) * 80 + nt * 16 + col;
                        if (w == 0) Sred[idx]  = acc[mt * 5 + nt][reg];
                        else        Sred[idx] += acc[mt * 5 + nt][reg];
                    }
        }
        __syncthreads();
    }
    float* dst = &Spart[(size_t)(n * 16 + tc) * 6400];
    for (int e = tid; e < 6400; e += 256) dst[e] = Sred[e];
}

// ---------------------------------------------------------------------------
// k2b: grid = (32 n x 5 w2-groups). Sum 16 partials, /75, column softmax
// over w1 with 16-lane shuffle trees; write BtT[n][80][96] = att^T.
// ---------------------------------------------------------------------------
__global__ __launch_bounds__(256) void k2b_softmax(
    const float* __restrict__ Spart, u16* __restrict__ BtT)
{
    __shared__ float S2[75][17];                  // [w1][w2l], pad to 17
    const int b = blockIdx.x;
    const int n = b / 5, w2g = b - n * 5;
    const int w2base = w2g * 16;
    const int tid = threadIdx.x;

    // phase 1: ks-reduction, 1200 elems
    for (int e = tid; e < 1200; e += 256) {
        const int w1 = e >> 4, w2l = e & 15;
        const float* sp = &Spart[(size_t)(n * 16) * 6400 + w1 * 80 + w2base + w2l];
        float s = 0.f;
        #pragma unroll
        for (int ks = 0; ks < 16; ++ks) s += sp[(size_t)ks * 6400];
        S2[w1][w2l] = s * (1.0f / 75.0f);
    }
    __syncthreads();

    // phase 2: softmax over w1, 16 lanes per column (cols are lane-contiguous)
    const int w2l = tid >> 4, j = tid & 15;
    float m = -1e30f;
    for (int w1 = j; w1 < 75; w1 += 16) m = fmaxf(m, S2[w1][w2l]);
    #pragma unroll
    for (int off = 8; off; off >>= 1) m = fmaxf(m, __shfl_xor(m, off, 16));
    float s = 0.f;
    for (int w1 = j; w1 < 75; w1 += 16) {
        const float e = __expf(S2[w1][w2l] - m);
        S2[w1][w2l] = e;
        s += e;
    }
    #pragma unroll
    for (int off = 8; off; off >>= 1) s += __shfl_xor(s, off, 16);
    const float r = 1.0f / s;
    for (int w1 = j; w1 < 75; w1 += 16) S2[w1][w2l] *= r;
    __syncthreads();

    // phase 3: store BtT rows w2base..w2base+15 (w2>=75 or v>=25 -> 0)
    for (int e = tid; e < 1536; e += 256) {
        const int wl = e / 96, k = e - wl * 96;
        const int i = k >> 5, v = k & 31;
        const int w2 = w2base + wl;
        const float val = (w2 < 75 && v < 25) ? S2[i * 25 + v][wl] : 0.f;
        BtT[((size_t)n * 80 + w2) * 96 + k] = f2b(val);
    }
}

// ---------------------------------------------------------------------------
// k3: MFMA graph contraction, operand-swapped: D[w][c] (row=w, col=c).
// Stores sum12[n][t][25v][3ww][16c] — 16-lane 32B segments, c innermost.
// ---------------------------------------------------------------------------
__global__ __launch_bounds__(256, 2) void k3_graph(
    const u16* __restrict__ hcn, const u16* __restrict__ BtA,
    const u16* __restrict__ BtT, u16* __restrict__ sum12)
{
    __shared__ u16 Bt[80 * 392];   // row stride 392 u16 = 784 B (2-way banks)
    const int b    = blockIdx.x;
    const int n    = b >> 4;
    const int tblk = (b & 15) << 5;
    const int tid  = threadIdx.x;

    for (int e = tid; e < 3840; e += 256) {             // stage Bt (uint4)
        int row = e / 48, cs = e - row * 48;
        uint4 val;
        if (cs < 36) val = *(const uint4*)&BtA[row * 288 + cs * 8];
        else         val = *(const uint4*)&BtT[((size_t)n * 80 + row) * 96 + (cs - 36) * 8];
        *(uint4*)&Bt[row * 392 + cs * 8] = val;
    }
    __syncthreads();

    const int wave = tid >> 6, lane = tid & 63;
    const int c = lane & 15, q = lane >> 4;
    const int tb = tblk + wave * 8;

    for (int tt = 0; tt < 8; tt += 2) {
        const int t0 = tb + tt, t1 = t0 + 1;
        bf16x8 a0[12], a1[12];
        #pragma unroll
        for (int r = 0; r < 12; ++r) {
            const int g = r / 3, i = r - g * 3;
            const size_t rowb = ((size_t)n * 64 + g * 16 + c) * 512;
            const int tp0 = t0 + i - 1, tp1 = t1 + i - 1;
            a0[r] = (tp0 >= 0 && tp0 < 512)
                  ? *(const bf16x8*)&hcn[(rowb + tp0) * 32 + q * 8] : (bf16x8)(short)0;
            a1[r] = (tp1 >= 0 && tp1 < 512)
                  ? *(const bf16x8*)&hcn[(rowb + tp1) * 32 + q * 8] : (bf16x8)(short)0;
        }
        #pragma unroll 1
        for (int nt = 0; nt < 5; ++nt) {
            f32x4 acc0 = {0.f, 0.f, 0.f, 0.f};
            f32x4 acc1 = {0.f, 0.f, 0.f, 0.f};
            const u16* bp = &Bt[(nt * 16 + c) * 392 + q * 8];
            #pragma unroll
            for (int r = 0; r < 12; ++r) {
                bf16x8 bf = *(const bf16x8*)(bp + r * 32);
                // swapped: A = Bt rows (w), B = hcn cols (c) -> D[w][c]
                acc0 = __builtin_amdgcn_mfma_f32_16x16x32_bf16(bf, a0[r], acc0, 0, 0, 0);
                acc1 = __builtin_amdgcn_mfma_f32_16x16x32_bf16(bf, a1[r], acc1, 0, 0, 0);
            }
            // D: row = q*4+reg = w, col = lane&15 = c
            const size_t tb0 = ((size_t)n * 512 + t0) * 1200;
            const size_t tb1 = ((size_t)n * 512 + t1) * 1200;
            #pragma unroll
            for (int reg = 0; reg < 4; ++reg) {
                const int w = nt * 16 + q * 4 + reg;
                if (w < 75) {
                    const int ww = (w >= 50) ? 2 : ((w >= 25) ? 1 : 0);
                    const int v  = w - ww * 25;
                    const int off = (v * 3 + ww) * 16 + c;
                    sum12[tb0 + off] = f2b(acc0[reg]);
                    sum12[tb1 + off] = f2b(acc1[reg]);
                }
            }
        }
    }
}

// ---------------------------------------------------------------------------
// k4: MFMA conv3d(1,3,1) + bias + BN + residual + relu.  (round-7 config)
// Block = (n, 8 t's). k = ww*16+c (pad 64). Epilogue via Csh[64][204] f32.
// ---------------------------------------------------------------------------
__global__ __launch_bounds__(256, 3) void k4_out(
    const u16* __restrict__ sum12,
    const float* __restrict__ ow, const float* __restrict__ obias,
    const float* __restrict__ bg, const float* __restrict__ bb,
    const float* __restrict__ bm, const float* __restrict__ bv,
    const float* __restrict__ x, float* __restrict__ out)
{
    __shared__ __align__(16) char smem[64 * 204 * 4];   // 52,224 B union
    u16*   Bsh = (u16*)smem;                            // [256 col][64 k] swz
    float* Csh = (float*)smem;                          // [64 o][204]
    char*  BshB = smem;

    const int b    = blockIdx.x;
    const int n    = b >> 6;
    const int t0   = (b & 63) << 3;
    const int tid  = threadIdx.x;
    const int wave = tid >> 6, lane = tid & 63;
    const int q    = lane >> 4, c15 = lane & 15;

    // zero pad chunks: kpad (j=6,7 all cols) + vpad cols (all 8 chunks).
    {
        uint4 z; z.x = 0u; z.y = 0u; z.z = 0u; z.w = 0u;
        for (int e = tid; e < 960; e += 256) {
            int col, j;
            if (e < 512) { col = e >> 1; j = 6 + (e & 1); }
            else {
                const int r2 = e - 512;
                const int cc = r2 >> 3; j = r2 & 7;
                const int tl = cc / 7, pv = cc - tl * 7;
                col = tl * 32 + 25 + pv;
            }
            *(uint4*)(BshB + col * 128 + ((j * 16) ^ ((col & 7) << 4))) = z;
        }
    }
    // stage valid rows (t, v<25): 6 uint4 per (t,v); fully contiguous reads.
    for (int e = tid; e < 1200; e += 256) {
        const int j  = e % 6;
        const int rv = e / 6;                     // tl*25 + v
        const int tl = (rv * 41) >> 10;
        const int v  = rv - tl * 25;
        const uint4 val = *(const uint4*)
            &sum12[((size_t)n * 512 + t0 + tl) * 1200 + v * 48 + j * 8];
        const int col = tl * 32 + v;
        *(uint4*)(BshB + col * 128 + ((j * 16) ^ ((col & 7) << 4))) = val;
    }

    // W2 A-fragments: A[o][k], k = ww*16+c (48 real, pad to 64 with zeros).
    bf16x8 wfrag[4][2];
    #pragma unroll
    for (int mt = 0; mt < 4; ++mt) {
        const int o = mt * 16 + c15;
        #pragma unroll
        for (int ks = 0; ks < 2; ++ks) {
            bf16x8 f;
            #pragma unroll
            for (int j = 0; j < 8; ++j) {
                const int k = ks * 32 + q * 8 + j;
                const int cc = k & 15, ww = k >> 4;
                f[j] = (k < 48) ? (short)f2b(ow[o * 48 + cc * 3 + ww]) : (short)0;
            }
            wfrag[mt][ks] = f;
        }
    }
    // BN/bias folded: y_pre = acc*scl + shf2, shf2 = (bias - mean)*scl + beta.
    float scl[4][4], shf2[4][4];
    #pragma unroll
    for (int mt = 0; mt < 4; ++mt)
        #pragma unroll
        for (int reg = 0; reg < 4; ++reg) {
            const int o = mt * 16 + q * 4 + reg;
            const float s = bg[o] * rsqrtf(bv[o] + 1e-5f);
            scl[mt][reg]  = s;
            shf2[mt][reg] = bb[o] + (obias[o] - bm[o]) * s;
        }
    __syncthreads();

    f32x4 acc[4][4];
    #pragma unroll
    for (int ct = 0; ct < 4; ++ct)
        #pragma unroll
        for (int mt = 0; mt < 4; ++mt)
            acc[ct][mt] = (f32x4){0.f, 0.f, 0.f, 0.f};

    const int wb = wave * 64;
    #pragma unroll
    for (int ct = 0; ct < 4; ++ct) {
        const int col = wb + ct * 16 + c15;
        const int swz = (col & 7) << 4;
        const char* rp = BshB + col * 128;
        const bf16x8 b0 = *(const bf16x8*)(rp + ((q * 16) ^ swz));
        const bf16x8 b1 = *(const bf16x8*)(rp + ((64 + q * 16) ^ swz));
        #pragma unroll
        for (int mt = 0; mt < 4; ++mt) {
            acc[ct][mt] = __builtin_amdgcn_mfma_f32_16x16x32_bf16(
                wfrag[mt][0], b0, acc[ct][mt], 0, 0, 0);
            acc[ct][mt] = __builtin_amdgcn_mfma_f32_16x16x32_bf16(
                wfrag[mt][1], b1, acc[ct][mt], 0, 0, 0);
        }
    }
    __syncthreads();                              // Bsh reads done

    // acc (+BN) -> Csh[o][tl*25+v]; stride 204 => q-groups on banks 0/16.
    #pragma unroll
    for (int ct = 0; ct < 4; ++ct) {
        const int col = wb + ct * 16 + c15;
        const int tl = col >> 5, v = col & 31;
        if (v < 25) {
            const int cc = tl * 25 + v;
            #pragma unroll
            for (int mt = 0; mt < 4; ++mt)
                #pragma unroll
                for (int reg = 0; reg < 4; ++reg) {
                    const int o = mt * 16 + q * 4 + reg;
                    Csh[o * 204 + cc] =
                        acc[ct][mt][reg] * scl[mt][reg] + shf2[mt][reg];
                }
        }
    }
    __syncthreads();

    // coalesced epilogue: float4 x-residual + relu + float4 out store.
    for (int e = tid; e < 3200; e += 256) {
        const int o = e / 50, jj = e - o * 50;
        const size_t gidx = (((size_t)n * 64 + o) * 512 + t0) * 25 + jj * 4;
        const float4 xv = *(const float4*)&x[gidx];
        const float* cp = &Csh[o * 204 + jj * 4];
        float4 yv;
        yv.x = fmaxf(cp[0] + xv.x, 0.f);
        yv.y = fmaxf(cp[1] + xv.y, 0.f);
        yv.z = fmaxf(cp[2] + xv.z, 0.f);
        yv.w = fmaxf(cp[3] + xv.w, 0.f);
        *(float4*)&out[gidx] = yv;
    }
}

// ---------------------------------------------------------------------------
extern "C" void kernel_launch(void* const* d_in, const int* in_sizes, int n_in,
                              void* d_out, int out_size, void* d_ws, size_t ws_size,
                              hipStream_t stream)
{
    const float* x  = (const float*)d_in[0];
    const float* A  = (const float*)d_in[1];
    const float* PA = (const float*)d_in[2];
    const float* wa = (const float*)d_in[3];
    const float* ba = (const float*)d_in[4];
    const float* wd = (const float*)d_in[5];
    const float* bd = (const float*)d_in[6];
    const float* wc = (const float*)d_in[7];
    const float* bc = (const float*)d_in[8];
    const float* ow = (const float*)d_in[9];
    const float* ob = (const float*)d_in[10];
    const float* bg = (const float*)d_in[11];
    const float* bb = (const float*)d_in[12];
    const float* bm = (const float*)d_in[13];
    const float* bv = (const float*)d_in[14];
    float* out = (float*)d_out;

    char* ws = (char*)d_ws;
    u16*   a1o   = (u16*)(ws);                           // 13,158,400 B
    u16*   hcn   = (u16*)(ws + 13158400);                // 67,108,864 B
    u16*   sum12 = (u16*)(ws + 80267264);                // 39,321,600 B (k3->k4)
    float* Spart = (float*)(ws + 80267264);              // 13,107,200 B (k2a->k2b)
    u16*   BtA   = (u16*)(ws + 130598912);               // 46,080 B
    u16*   BtT   = (u16*)(ws + 130644992);               // 491,520 B
    // total 131,136,512 B (sum12 overlaps Spart: disjoint lifetimes)

    k0_bta    <<<90,   256, 0, stream>>>(A, PA, BtA);
    k1_conv80 <<<512,  256, 0, stream>>>(x, wa, ba, wd, bd, wc, bc, a1o, hcn);
    k2a_mfma  <<<512,  256, 0, stream>>>(a1o, Spart);
    k2b_softmax<<<160, 256, 0, stream>>>(Spart, BtT);
    k3_graph  <<<512,  256, 0, stream>>>(hcn, BtA, BtT, sum12);
    k4_out    <<<2048, 256, 0, stream>>>(sum12, ow, ob, bg, bb, bm, bv, x, out);
}

// Round 10
// 389.515 us; speedup vs baseline: 1.2214x; 1.0665x over previous
//
#include <hip/hip_runtime.h>
#include <hip/hip_bf16.h>

// ============================================================================
// ConvTemporalGraphical — round 14: r13 + k3 frag rotation + k2a parallel
// reduce. k0/k1/k2b/k4 are r13 verbatim (k4 = the confirmed-best r7 config).
//
//   k0: BtA[80w][288k] = Aeff^T bf16, K regions r=g*3+i, k=r*32+v (padded).
//   k1: MFMA 80-ch 1x1 conv (round-5 structure).
//   k2a: MFMA Gram; NEW: 2-buffer parallel cross-wave reduce (2 barriers,
//        waves 0/1 write Sred/Sred2, waves 2/3 add, store sums both).
//   k2b: 160 blocks (n x 5 w2-groups), shuffle-tree column softmax.
//   k3: MFMA graph contraction; NEW: rotating frag[g][0..3] register window
//        over tp in [t0-1, t0+2] -> 8 scattered hcn loads per t-pair (was 24).
//   k4: MFMA conv3d + bias + BN + residual + relu (r7 config: 3 blk/CU,
//        single-pass epilogue, 800B regions, no relabel, no nt).
//
// ws layout (sum12t overlaps Spart — disjoint lifetimes, stream-ordered):
//   a1o 0..13,158,400 | hcn ..80,267,264 | sum12t/Spart 80,267,264..
//   (+39,321,600 / +13,107,200) | BtA 130,598,912 | BtT 130,644,992
//   => total 131,136,512 B.
// ============================================================================

typedef unsigned short u16;
typedef unsigned int   u32;
typedef __attribute__((ext_vector_type(8))) short bf16x8;
typedef __attribute__((ext_vector_type(4))) float f32x4;

__device__ __forceinline__ float b2f(u32 u) {
    union { u32 i; float f; } x; x.i = (u & 0xffffu) << 16; return x.f;
}
__device__ __forceinline__ u16 f2b(float f) {
    union { float f; u32 i; } x; x.f = f;
    u32 i = x.i;
    return (u16)((i + 0x7fffu + ((i >> 16) & 1u)) >> 16);   // RNE
}
__device__ __forceinline__ u32 pack2(float a, float b) {
    return (u32)f2b(a) | ((u32)f2b(b) << 16);
}

// ---------------------------------------------------------------------------
// k0: BtA = Aeff^T with (g,i)-region K layout, zero-padded.
// ---------------------------------------------------------------------------
__global__ __launch_bounds__(256) void k0_bta(
    const float* __restrict__ A, const float* __restrict__ PA,
    u16* __restrict__ BtA)
{
    int e = blockIdx.x * 256 + threadIdx.x;
    if (e >= 80 * 288) return;
    int w = e / 288, k = e - w * 288;
    int r = k >> 5, v = k & 31, g = r / 3, i = r - g * 3;
    float val = 0.f;
    if (v < 25 && w < 75) {
        int idx = (g * 75 + i * 25 + v) * 75 + w;
        val = A[idx] + PA[idx];
    }
    BtA[e] = f2b(val);
}

// ---------------------------------------------------------------------------
// k1: MFMA 80-ch 1x1 conv. Block = (n, 32 t's), 256 thr (4 waves), 4 stages.
// ---------------------------------------------------------------------------
__global__ __launch_bounds__(256, 2) void k1_conv80(
    const float* __restrict__ x,
    const float* __restrict__ wa, const float* __restrict__ ba,
    const float* __restrict__ wd, const float* __restrict__ bd,
    const float* __restrict__ wc, const float* __restrict__ bc,
    u16* __restrict__ a1o, u16* __restrict__ hcn)
{
    __shared__ __align__(16) u16 Xt[256 * 64];    // 32,768 B, [col][c] swizzled
    __shared__ __align__(16) u16 Csh[80 * 264];   // 42,240 B, [o][col] stride 264
    char* XtB = (char*)Xt;

    const int b    = blockIdx.x;
    const int n    = b >> 4;
    const int t0   = (b & 15) << 5;               // 32 t's per block
    const int tid  = threadIdx.x;
    const int wave = tid >> 6, lane = tid & 63;
    const int q    = lane >> 4, r = lane & 15;

    // --- per-block preload: W fragments (B-operand layout) + bias ---
    bf16x8 wfrag[5][2];
    float  breg[5];
    #pragma unroll
    for (int mt = 0; mt < 5; ++mt) {
        const int o = mt * 16 + r;
        const float* src = (o < 16) ? (wa + o * 64)
                         : (o < 32) ? (wd + (o - 16) * 64)
                                    : (wc + (o - 32) * 64);
        breg[mt] = (o < 16) ? ba[o] : (o < 32) ? bd[o - 16] : bc[o - 32];
        #pragma unroll
        for (int ks = 0; ks < 2; ++ks) {
            bf16x8 f;
            #pragma unroll
            for (int j = 0; j < 8; ++j)
                f[j] = (short)f2b(src[ks * 32 + q * 8 + j]);
            wfrag[mt][ks] = f;
        }
    }

    // --- a1o t-pad rows (ws is poisoned each launch) ---
    if (t0 == 0) {
        uint4 z; z.x = 0u; z.y = 0u; z.z = 0u; z.w = 0u;
        for (int e = tid; e < 50; e += 256)
            *(uint4*)&a1o[((size_t)n * 514) * 400 + e * 8] = z;
    }
    if (t0 == 480) {
        uint4 z; z.x = 0u; z.y = 0u; z.z = 0u; z.w = 0u;
        for (int e = tid; e < 50; e += 256)
            *(uint4*)&a1o[((size_t)n * 514 + 513) * 400 + e * 8] = z;
    }

    // --- zero Xt pad cols once (v = 25..31 per t; full 128B rows) ---
    {
        uint4 z; z.x = 0u; z.y = 0u; z.z = 0u; z.w = 0u;
        for (int e = tid; e < 448; e += 256) {
            const int pc = e >> 3, ch = e & 7;
            const int tl = pc / 7, pv = pc - tl * 7;
            const int col = tl * 32 + 25 + pv;
            *(uint4*)(XtB + col * 128 + ch * 16) = z;
        }
    }

    auto epilogue = [&](int tbp) {
        for (int e = tid; e < 2048; e += 256) {
            const int cc  = e >> 5;
            const int rem = e & 31;
            const int tl  = rem >> 2, v0 = (rem & 3) << 3;
            const int o   = (cc < 48) ? cc + 32 : cc - 32;
            uint4 pk = *(const uint4*)&Csh[o * 264 + tl * 32 + v0];
            *(uint4*)&hcn[(((size_t)n * 64 + cc) * 512 + (tbp + tl)) * 32 + v0] = pk;
        }
        for (int e = tid; e < 400; e += 256) {
            const int tv = e >> 1, h = (e & 1) << 3;
            const int tl = (tv * 41) >> 10;
            const int v  = tv - tl * 25;
            const int cb = tl * 32 + v;
            u16 a[8];
            #pragma unroll
            for (int k = 0; k < 8; ++k) a[k] = Csh[(h + k) * 264 + cb];
            uint4 pk;
            pk.x = (u32)a[0] | ((u32)a[1] << 16);
            pk.y = (u32)a[2] | ((u32)a[3] << 16);
            pk.z = (u32)a[4] | ((u32)a[5] << 16);
            pk.w = (u32)a[6] | ((u32)a[7] << 16);
            *(uint4*)&a1o[(((size_t)n * 514 + (tbp + tl + 1)) * 25 + v) * 16 + h] = pk;
        }
    };

    for (int s = 0; s < 4; ++s) {
        const int tb = t0 + s * 8;

        if (s > 0) epilogue(tb - 8);
        for (int e = tid; e < 400; e += 256) {
            const int co = e / 50;
            const int tq = e - co * 50;
            const float* gp = x + (((size_t)n * 64 + co * 8) * 512 + tb) * 25 + tq * 4;
            float fl[32];
            #pragma unroll
            for (int i = 0; i < 8; ++i) {
                const float4 t4 = *(const float4*)(gp + (size_t)i * 12800);
                fl[i * 4 + 0] = t4.x; fl[i * 4 + 1] = t4.y;
                fl[i * 4 + 2] = t4.z; fl[i * 4 + 3] = t4.w;
            }
            #pragma unroll
            for (int j = 0; j < 4; ++j) {
                const int tv  = tq * 4 + j;
                const int tl  = (tv * 41) >> 10;
                const int col = tl * 32 + (tv - tl * 25);
                uint4 pk;
                pk.x = pack2(fl[0 * 4 + j], fl[1 * 4 + j]);
                pk.y = pack2(fl[2 * 4 + j], fl[3 * 4 + j]);
                pk.z = pack2(fl[4 * 4 + j], fl[5 * 4 + j]);
                pk.w = pack2(fl[6 * 4 + j], fl[7 * 4 + j]);
                *(uint4*)(XtB + col * 128 + ((co * 16) ^ ((col & 7) << 4))) = pk;
            }
        }
        __syncthreads();

        {
            f32x4 acc[4][5];
            #pragma unroll
            for (int a_ = 0; a_ < 4; ++a_)
                #pragma unroll
                for (int m_ = 0; m_ < 5; ++m_)
                    acc[a_][m_] = (f32x4){0.f, 0.f, 0.f, 0.f};

            #pragma unroll
            for (int nt4 = 0; nt4 < 4; ++nt4) {
                const int col = (wave * 4 + nt4) * 16 + r;
                const int swz = (col & 7) << 4;
                const char* rowp = (const char*)Xt + col * 128;
                const bf16x8 x0 = *(const bf16x8*)(rowp + ((q * 16) ^ swz));
                const bf16x8 x1 = *(const bf16x8*)(rowp + ((64 + q * 16) ^ swz));
                #pragma unroll
                for (int mt = 0; mt < 5; ++mt) {
                    acc[nt4][mt] = __builtin_amdgcn_mfma_f32_16x16x32_bf16(
                        x0, wfrag[mt][0], acc[nt4][mt], 0, 0, 0);
                    acc[nt4][mt] = __builtin_amdgcn_mfma_f32_16x16x32_bf16(
                        x1, wfrag[mt][1], acc[nt4][mt], 0, 0, 0);
                }
            }
            #pragma unroll
            for (int nt4 = 0; nt4 < 4; ++nt4) {
                const int colb = (wave * 4 + nt4) * 16 + q * 4;
                #pragma unroll
                for (int mt = 0; mt < 5; ++mt) {
                    const int o = mt * 16 + r;
                    const float bi = breg[mt];
                    uint2 pr;
                    pr.x = pack2(acc[nt4][mt][0] + bi, acc[nt4][mt][1] + bi);
                    pr.y = pack2(acc[nt4][mt][2] + bi, acc[nt4][mt][3] + bi);
                    *(uint2*)&Csh[o * 264 + colb] = pr;
                }
            }
        }
        __syncthreads();
    }
    epilogue(t0 + 24);
}

// ---------------------------------------------------------------------------
// k2a: MFMA Gram matrix. Block = (n, 32-t chunk), 4 waves split k.
// NEW: 2-buffer parallel cross-wave reduce (2 barriers instead of 4 serial).
// ---------------------------------------------------------------------------
__global__ __launch_bounds__(256, 2) void k2a_mfma(
    const u16* __restrict__ a1o, float* __restrict__ Spart)
{
    __shared__ u16 U[80 * 136];        // 21,760 B (stride 136: 2-way banks)
    __shared__ float Sred[80 * 80];    // 25,600 B
    __shared__ float Sred2[80 * 80];   // 25,600 B  (total 72,960 -> 2 blk/CU)
    const int b   = blockIdx.x;
    const int n   = b >> 4;
    const int tc  = b & 15;
    const int t0  = tc * 32;
    const int tid = threadIdx.x;
    const int wave = tid >> 6, lane = tid & 63;
    const int q = lane >> 4, col = lane & 15;

    f32x4 acc[25];
    #pragma unroll
    for (int i = 0; i < 25; ++i) acc[i] = (f32x4){0.f, 0.f, 0.f, 0.f};

    for (int s = 0; s < 4; ++s) {
        __syncthreads();                               // prior reads done
        for (int e = tid; e < 1280; e += 256) {        // stage 8 t's
            int row = e >> 4, c8 = (e & 15) << 3;
            uint4 val; val.x = 0u; val.y = 0u; val.z = 0u; val.w = 0u;
            if (row < 75) {
                int i = row / 25, v = row - i * 25;
                int tl = c8 >> 4, o0 = c8 & 8;
                int tp = t0 + s * 8 + tl + i;          // padded t idx, 0..513
                val = *(const uint4*)&a1o[(((size_t)n * 514 + tp) * 25 + v) * 16 + o0];
            }
            *(uint4*)&U[row * 136 + c8] = val;
        }
        __syncthreads();

        const int k0 = wave * 32 + q * 8;
        bf16x8 fr[5];
        #pragma unroll
        for (int r = 0; r < 5; ++r)
            fr[r] = *(const bf16x8*)&U[(r * 16 + col) * 136 + k0];
        #pragma unroll
        for (int mt = 0; mt < 5; ++mt)
            #pragma unroll
            for (int nt = 0; nt < 5; ++nt)
                acc[mt * 5 + nt] = __builtin_amdgcn_mfma_f32_16x16x32_bf16(
                    fr[mt], fr[nt], acc[mt * 5 + nt], 0, 0, 0);
    }

    // parallel reduce: waves 0/1 write Sred/Sred2; waves 2/3 add into them.
    if (wave < 2) {
        float* S = (wave == 0) ? Sred : Sred2;
        #pragma unroll
        for (int mt = 0; mt < 5; ++mt)
            #pragma unroll
            for (int nt = 0; nt < 5; ++nt)
                #pragma unroll
                for (int reg = 0; reg < 4; ++reg)
                    S[(mt * 16 + q * 4 + reg) * 80 + nt * 16 + col] =
                        acc[mt * 5 + nt][reg];
    }
    __syncthreads();
    if (wave >= 2) {
        float* S = (wave == 2) ? Sred : Sred2;
        #pragma unroll
        for (int mt = 0; mt < 5; ++mt)
            #pragma unroll
            for (int nt = 0; nt < 5; ++nt)
                #pragma unroll
                for (int reg = 0; reg < 4; ++reg)
                    S[(mt * 16 + q * 4 + reg) * 80 + nt * 16 + col] +=
                        acc[mt * 5 + nt][reg];
    }
    __syncthreads();
    float* dst = &Spart[(size_t)(n * 16 + tc) * 6400];
    for (int e = tid; e < 6400; e += 256) dst[e] = Sred[e] + Sred2[e];
}

// ---------------------------------------------------------------------------
// k2b: grid = (32 n x 5 w2-groups). Sum 16 partials, /75, column softmax
// over w1 with 16-lane shuffle trees; write BtT[n][80][96] = att^T.
// ---------------------------------------------------------------------------
__global__ __launch_bounds__(256) void k2b_softmax(
    const float* __restrict__ Spart, u16* __restrict__ BtT)
{
    __shared__ float S2[75][17];                  // [w1][w2l], pad to 17
    const int b = blockIdx.x;
    const int n = b / 5, w2g = b - n * 5;
    const int w2base = w2g * 16;
    const int tid = threadIdx.x;

    // phase 1: ks-reduction, 1200 elems
    for (int e = tid; e < 1200; e += 256) {
        const int w1 = e >> 4, w2l = e & 15;
        const float* sp = &Spart[(size_t)(n * 16) * 6400 + w1 * 80 + w2base + w2l];
        float s = 0.f;
        #pragma unroll
        for (int ks = 0; ks < 16; ++ks) s += sp[(size_t)ks * 6400];
        S2[w1][w2l] = s * (1.0f / 75.0f);
    }
    __syncthreads();

    // phase 2: softmax over w1, 16 lanes per column (cols are lane-contiguous)
    const int w2l = tid >> 4, j = tid & 15;
    float m = -1e30f;
    for (int w1 = j; w1 < 75; w1 += 16) m = fmaxf(m, S2[w1][w2l]);
    #pragma unroll
    for (int off = 8; off; off >>= 1) m = fmaxf(m, __shfl_xor(m, off, 16));
    float s = 0.f;
    for (int w1 = j; w1 < 75; w1 += 16) {
        const float e = __expf(S2[w1][w2l] - m);
        S2[w1][w2l] = e;
        s += e;
    }
    #pragma unroll
    for (int off = 8; off; off >>= 1) s += __shfl_xor(s, off, 16);
    const float r = 1.0f / s;
    for (int w1 = j; w1 < 75; w1 += 16) S2[w1][w2l] *= r;
    __syncthreads();

    // phase 3: store BtT rows w2base..w2base+15 (w2>=75 or v>=25 -> 0)
    for (int e = tid; e < 1536; e += 256) {
        const int wl = e / 96, k = e - wl * 96;
        const int i = k >> 5, v = k & 31;
        const int w2 = w2base + wl;
        const float val = (w2 < 75 && v < 25) ? S2[i * 25 + v][wl] : 0.f;
        BtT[((size_t)n * 80 + w2) * 96 + k] = f2b(val);
    }
}

// ---------------------------------------------------------------------------
// k3: MFMA graph contraction, operand-swapped: D[w][c] (row=w, col=c).
// NEW: rotating frag window frag[g][0..3] over tp in [t0-1, t0+2]:
// 8 scattered hcn loads per t-pair (was 24); ds_read/MFMA counts unchanged.
// Stores sum12[n][t][25v][3ww][16c] — 16-lane 32B segments, c innermost.
// ---------------------------------------------------------------------------
__global__ __launch_bounds__(256, 2) void k3_graph(
    const u16* __restrict__ hcn, const u16* __restrict__ BtA,
    const u16* __restrict__ BtT, u16* __restrict__ sum12)
{
    __shared__ u16 Bt[80 * 392];   // row stride 392 u16 = 784 B (2-way banks)
    const int b    = blockIdx.x;
    const int n    = b >> 4;
    const int tblk = (b & 15) << 5;
    const int tid  = threadIdx.x;

    for (int e = tid; e < 3840; e += 256) {             // stage Bt (uint4)
        int row = e / 48, cs = e - row * 48;
        uint4 val;
        if (cs < 36) val = *(const uint4*)&BtA[row * 288 + cs * 8];
        else         val = *(const uint4*)&BtT[((size_t)n * 80 + row) * 96 + (cs - 36) * 8];
        *(uint4*)&Bt[row * 392 + cs * 8] = val;
    }
    __syncthreads();

    const int wave = tid >> 6, lane = tid & 63;
    const int c = lane & 15, q = lane >> 4;
    const int tb = tblk + wave * 8;

    auto hload = [&](int g, int tp) -> bf16x8 {
        if (tp < 0 || tp >= 512) return (bf16x8)(short)0;
        const size_t rowb = ((size_t)n * 64 + g * 16 + c) * 512;
        return *(const bf16x8*)&hcn[(rowb + tp) * 32 + q * 8];
    };

    // frag[g][s] holds hcn fragment at tp = t0 - 1 + s for current pair t0.
    bf16x8 frag[4][4];
    #pragma unroll
    for (int g = 0; g < 4; ++g) {
        frag[g][0] = hload(g, tb - 1);
        frag[g][1] = hload(g, tb);
        frag[g][2] = hload(g, tb + 1);
        frag[g][3] = hload(g, tb + 2);
    }

    #pragma unroll
    for (int tt = 0; tt < 8; tt += 2) {
        const int t0 = tb + tt, t1 = t0 + 1;
        #pragma unroll 1
        for (int nt = 0; nt < 5; ++nt) {
            f32x4 acc0 = {0.f, 0.f, 0.f, 0.f};
            f32x4 acc1 = {0.f, 0.f, 0.f, 0.f};
            const u16* bp = &Bt[(nt * 16 + c) * 392 + q * 8];
            #pragma unroll
            for (int g = 0; g < 4; ++g)
                #pragma unroll
                for (int i = 0; i < 3; ++i) {
                    const int r = g * 3 + i;
                    bf16x8 bf = *(const bf16x8*)(bp + r * 32);
                    // swapped: A = Bt rows (w), B = hcn cols (c) -> D[w][c]
                    acc0 = __builtin_amdgcn_mfma_f32_16x16x32_bf16(bf, frag[g][i],     acc0, 0, 0, 0);
                    acc1 = __builtin_amdgcn_mfma_f32_16x16x32_bf16(bf, frag[g][i + 1], acc1, 0, 0, 0);
                }
            // D: row = q*4+reg = w, col = lane&15 = c
            const size_t tb0 = ((size_t)n * 512 + t0) * 1200;
            const size_t tb1 = ((size_t)n * 512 + t1) * 1200;
            #pragma unroll
            for (int reg = 0; reg < 4; ++reg) {
                const int w = nt * 16 + q * 4 + reg;
                if (w < 75) {
                    const int ww = (w >= 50) ? 2 : ((w >= 25) ? 1 : 0);
                    const int v  = w - ww * 25;
                    const int off = (v * 3 + ww) * 16 + c;
                    sum12[tb0 + off] = f2b(acc0[reg]);
                    sum12[tb1 + off] = f2b(acc1[reg]);
                }
            }
        }
        if (tt < 6) {                          // shift window by 2 t's
            #pragma unroll
            for (int g = 0; g < 4; ++g) {
                frag[g][0] = frag[g][2];
                frag[g][1] = frag[g][3];
                frag[g][2] = hload(g, t0 + 3);
                frag[g][3] = hload(g, t0 + 4);
            }
        }
    }
}

// ---------------------------------------------------------------------------
// k4: MFMA conv3d(1,3,1) + bias + BN + residual + relu.  (round-7 config)
// Block = (n, 8 t's). k = ww*16+c (pad 64). Epilogue via Csh[64][204] f32.
// ---------------------------------------------------------------------------
__global__ __launch_bounds__(256, 3) void k4_out(
    const u16* __restrict__ sum12,
    const float* __restrict__ ow, const float* __restrict__ obias,
    const float* __restrict__ bg, const float* __restrict__ bb,
    const float* __restrict__ bm, const float* __restrict__ bv,
    const float* __restrict__ x, float* __restrict__ out)
{
    __shared__ __align__(16) char smem[64 * 204 * 4];   // 52,224 B union
    u16*   Bsh = (u16*)smem;                            // [256 col][64 k] swz
    float* Csh = (float*)smem;                          // [64 o][204]
    char*  BshB = smem;

    const int b    = blockIdx.x;
    const int n    = b >> 6;
    const int t0   = (b & 63) << 3;
    const int tid  = threadIdx.x;
    const int wave = tid >> 6, lane = tid & 63;
    const int q    = lane >> 4, c15 = lane & 15;

    // zero pad chunks: kpad (j=6,7 all cols) + vpad cols (all 8 chunks).
    {
        uint4 z; z.x = 0u; z.y = 0u; z.z = 0u; z.w = 0u;
        for (int e = tid; e < 960; e += 256) {
            int col, j;
            if (e < 512) { col = e >> 1; j = 6 + (e & 1); }
            else {
                const int r2 = e - 512;
                const int cc = r2 >> 3; j = r2 & 7;
                const int tl = cc / 7, pv = cc - tl * 7;
                col = tl * 32 + 25 + pv;
            }
            *(uint4*)(BshB + col * 128 + ((j * 16) ^ ((col & 7) << 4))) = z;
        }
    }
    // stage valid rows (t, v<25): 6 uint4 per (t,v); fully contiguous reads.
    for (int e = tid; e < 1200; e += 256) {
        const int j  = e % 6;
        const int rv = e / 6;                     // tl*25 + v
        const int tl = (rv * 41) >> 10;
        const int v  = rv - tl * 25;
        const uint4 val = *(const uint4*)
            &sum12[((size_t)n * 512 + t0 + tl) * 1200 + v * 48 + j * 8];
        const int col = tl * 32 + v;
        *(uint4*)(BshB + col * 128 + ((j * 16) ^ ((col & 7) << 4))) = val;
    }

    // W2 A-fragments: A[o][k], k = ww*16+c (48 real, pad to 64 with zeros).
    bf16x8 wfrag[4][2];
    #pragma unroll
    for (int mt = 0; mt < 4; ++mt) {
        const int o = mt * 16 + c15;
        #pragma unroll
        for (int ks = 0; ks < 2; ++ks) {
            bf16x8 f;
            #pragma unroll
            for (int j = 0; j < 8; ++j) {
                const int k = ks * 32 + q * 8 + j;
                const int cc = k & 15, ww = k >> 4;
                f[j] = (k < 48) ? (short)f2b(ow[o * 48 + cc * 3 + ww]) : (short)0;
            }
            wfrag[mt][ks] = f;
        }
    }
    // BN/bias folded: y_pre = acc*scl + shf2, shf2 = (bias - mean)*scl + beta.
    float scl[4][4], shf2[4][4];
    #pragma unroll
    for (int mt = 0; mt < 4; ++mt)
        #pragma unroll
        for (int reg = 0; reg < 4; ++reg) {
            const int o = mt * 16 + q * 4 + reg;
            const float s = bg[o] * rsqrtf(bv[o] + 1e-5f);
            scl[mt][reg]  = s;
            shf2[mt][reg] = bb[o] + (obias[o] - bm[o]) * s;
        }
    __syncthreads();

    f32x4 acc[4][4];
    #pragma unroll
    for (int ct = 0; ct < 4; ++ct)
        #pragma unroll
        for (int mt = 0; mt < 4; ++mt)
            acc[ct][mt] = (f32x4){0.f, 0.f, 0.f, 0.f};

    const int wb = wave * 64;
    #pragma unroll
    for (int ct = 0; ct < 4; ++ct) {
        const int col = wb + ct * 16 + c15;
        const int swz = (col & 7) << 4;
        const char* rp = BshB + col * 128;
        const bf16x8 b0 = *(const bf16x8*)(rp + ((q * 16) ^ swz));
        const bf16x8 b1 = *(const bf16x8*)(rp + ((64 + q * 16) ^ swz));
        #pragma unroll
        for (int mt = 0; mt < 4; ++mt) {
            acc[ct][mt] = __builtin_amdgcn_mfma_f32_16x16x32_bf16(
                wfrag[mt][0], b0, acc[ct][mt], 0, 0, 0);
            acc[ct][mt] = __builtin_amdgcn_mfma_f32_16x16x32_bf16(
                wfrag[mt][1], b1, acc[ct][mt], 0, 0, 0);
        }
    }
    __syncthreads();                              // Bsh reads done

    // acc (+BN) -> Csh[o][tl*25+v]; stride 204 => q-groups on banks 0/16.
    #pragma unroll
    for (int ct = 0; ct < 4; ++ct) {
        const int col = wb + ct * 16 + c15;
        const int tl = col >> 5, v = col & 31;
        if (v < 25) {
            const int cc = tl * 25 + v;
            #pragma unroll
            for (int mt = 0; mt < 4; ++mt)
                #pragma unroll
                for (int reg = 0; reg < 4; ++reg) {
                    const int o = mt * 16 + q * 4 + reg;
                    Csh[o * 204 + cc] =
                        acc[ct][mt][reg] * scl[mt][reg] + shf2[mt][reg];
                }
        }
    }
    __syncthreads();

    // coalesced epilogue: float4 x-residual + relu + float4 out store.
    for (int e = tid; e < 3200; e += 256) {
        const int o = e / 50, jj = e - o * 50;
        const size_t gidx = (((size_t)n * 64 + o) * 512 + t0) * 25 + jj * 4;
        const float4 xv = *(const float4*)&x[gidx];
        const float* cp = &Csh[o * 204 + jj * 4];
        float4 yv;
        yv.x = fmaxf(cp[0] + xv.x, 0.f);
        yv.y = fmaxf(cp[1] + xv.y, 0.f);
        yv.z = fmaxf(cp[2] + xv.z, 0.f);
        yv.w = fmaxf(cp[3] + xv.w, 0.f);
        *(float4*)&out[gidx] = yv;
    }
}

// ---------------------------------------------------------------------------
extern "C" void kernel_launch(void* const* d_in, const int* in_sizes, int n_in,
                              void* d_out, int out_size, void* d_ws, size_t ws_size,
                              hipStream_t stream)
{
    const float* x  = (const float*)d_in[0];
    const float* A  = (const float*)d_in[1];
    const float* PA = (const float*)d_in[2];
    const float* wa = (const float*)d_in[3];
    const float* ba = (const float*)d_in[4];
    const float* wd = (const float*)d_in[5];
    const float* bd = (const float*)d_in[6];
    const float* wc = (const float*)d_in[7];
    const float* bc = (const float*)d_in[8];
    const float* ow = (const float*)d_in[9];
    const float* ob = (const float*)d_in[10];
    const float* bg = (const float*)d_in[11];
    const float* bb = (const float*)d_in[12];
    const float* bm = (const float*)d_in[13];
    const float* bv = (const float*)d_in[14];
    float* out = (float*)d_out;

    char* ws = (char*)d_ws;
    u16*   a1o   = (u16*)(ws);                           // 13,158,400 B
    u16*   hcn   = (u16*)(ws + 13158400);                // 67,108,864 B
    u16*   sum12 = (u16*)(ws + 80267264);                // 39,321,600 B (k3->k4)
    float* Spart = (float*)(ws + 80267264);              // 13,107,200 B (k2a->k2b)
    u16*   BtA   = (u16*)(ws + 130598912);               // 46,080 B
    u16*   BtT   = (u16*)(ws + 130644992);               // 491,520 B
    // total 131,136,512 B (sum12 overlaps Spart: disjoint lifetimes)

    k0_bta    <<<90,   256, 0, stream>>>(A, PA, BtA);
    k1_conv80 <<<512,  256, 0, stream>>>(x, wa, ba, wd, bd, wc, bc, a1o, hcn);
    k2a_mfma  <<<512,  256, 0, stream>>>(a1o, Spart);
    k2b_softmax<<<160, 256, 0, stream>>>(Spart, BtT);
    k3_graph  <<<512,  256, 0, stream>>>(hcn, BtA, BtT, sum12);
    k4_out    <<<2048, 256, 0, stream>>>(sum12, ow, ob, bg, bb, bm, bv, x, out);
}

// Round 11
// 380.698 us; speedup vs baseline: 1.2497x; 1.0232x over previous
//
#include <hip/hip_runtime.h>
#include <hip/hip_bf16.h>

// ============================================================================
// ConvTemporalGraphical — round 15: k3+k4 FUSED (k34). Deletes the sum12
// HBM round-trip (39.3 MB write + 39.3 MB read), one launch, k4's stage
// phase. k0/k1/k2a/k2b are r14 verbatim.
//
//   k0: BtA[80w][288k] = Aeff^T bf16, K regions r=g*3+i, k=r*32+v (padded).
//   k1: MFMA 80-ch 1x1 conv (round-5 structure).
//   k2a: MFMA Gram, 2-buffer parallel cross-wave reduce.
//   k2b: 160 blocks (n x 5 w2-groups), shuffle-tree column softmax.
//   k34: block=(n, 8 t's), 2048 blocks, LDS = 81,920 B exactly (2 blk/CU):
//        Bt[80][392] 62,720 B | tile[8][1200] bf16 19,200 B.
//        phase A: stage Bt; phase B (per wave, one t-pair): r14-k3 MFMAs ->
//        f2b -> LDS tile (same (v*3+ww)*16+c layout sum12 had, so numerics
//        are bit-identical); phase C: r13-k4 MFMAs reading contiguous 16B
//        B-frags from tile (ks=1,q>=2 sub-frags are k>=48: wfrag=0, read
//        clamped in-bounds); Csh[64][204] f32 overlays dead Bt; phase D:
//        float4 x-residual + relu + float4 out (800B regions, r7-quality).
//
// ws: a1o 0..13,158,400 | hcn ..80,267,264 | Spart 80,267,264..93,374,464 |
//     BtA 130,598,912 | BtT 130,644,992  (sum12 region now unused)
// ============================================================================

typedef unsigned short u16;
typedef unsigned int   u32;
typedef __attribute__((ext_vector_type(8))) short bf16x8;
typedef __attribute__((ext_vector_type(4))) float f32x4;

__device__ __forceinline__ float b2f(u32 u) {
    union { u32 i; float f; } x; x.i = (u & 0xffffu) << 16; return x.f;
}
__device__ __forceinline__ u16 f2b(float f) {
    union { float f; u32 i; } x; x.f = f;
    u32 i = x.i;
    return (u16)((i + 0x7fffu + ((i >> 16) & 1u)) >> 16);   // RNE
}
__device__ __forceinline__ u32 pack2(float a, float b) {
    return (u32)f2b(a) | ((u32)f2b(b) << 16);
}

// ---------------------------------------------------------------------------
// k0: BtA = Aeff^T with (g,i)-region K layout, zero-padded.
// ---------------------------------------------------------------------------
__global__ __launch_bounds__(256) void k0_bta(
    const float* __restrict__ A, const float* __restrict__ PA,
    u16* __restrict__ BtA)
{
    int e = blockIdx.x * 256 + threadIdx.x;
    if (e >= 80 * 288) return;
    int w = e / 288, k = e - w * 288;
    int r = k >> 5, v = k & 31, g = r / 3, i = r - g * 3;
    float val = 0.f;
    if (v < 25 && w < 75) {
        int idx = (g * 75 + i * 25 + v) * 75 + w;
        val = A[idx] + PA[idx];
    }
    BtA[e] = f2b(val);
}

// ---------------------------------------------------------------------------
// k1: MFMA 80-ch 1x1 conv. Block = (n, 32 t's), 256 thr (4 waves), 4 stages.
// ---------------------------------------------------------------------------
__global__ __launch_bounds__(256, 2) void k1_conv80(
    const float* __restrict__ x,
    const float* __restrict__ wa, const float* __restrict__ ba,
    const float* __restrict__ wd, const float* __restrict__ bd,
    const float* __restrict__ wc, const float* __restrict__ bc,
    u16* __restrict__ a1o, u16* __restrict__ hcn)
{
    __shared__ __align__(16) u16 Xt[256 * 64];    // 32,768 B, [col][c] swizzled
    __shared__ __align__(16) u16 Csh[80 * 264];   // 42,240 B, [o][col] stride 264
    char* XtB = (char*)Xt;

    const int b    = blockIdx.x;
    const int n    = b >> 4;
    const int t0   = (b & 15) << 5;               // 32 t's per block
    const int tid  = threadIdx.x;
    const int wave = tid >> 6, lane = tid & 63;
    const int q    = lane >> 4, r = lane & 15;

    // --- per-block preload: W fragments (B-operand layout) + bias ---
    bf16x8 wfrag[5][2];
    float  breg[5];
    #pragma unroll
    for (int mt = 0; mt < 5; ++mt) {
        const int o = mt * 16 + r;
        const float* src = (o < 16) ? (wa + o * 64)
                         : (o < 32) ? (wd + (o - 16) * 64)
                                    : (wc + (o - 32) * 64);
        breg[mt] = (o < 16) ? ba[o] : (o < 32) ? bd[o - 16] : bc[o - 32];
        #pragma unroll
        for (int ks = 0; ks < 2; ++ks) {
            bf16x8 f;
            #pragma unroll
            for (int j = 0; j < 8; ++j)
                f[j] = (short)f2b(src[ks * 32 + q * 8 + j]);
            wfrag[mt][ks] = f;
        }
    }

    // --- a1o t-pad rows (ws is poisoned each launch) ---
    if (t0 == 0) {
        uint4 z; z.x = 0u; z.y = 0u; z.z = 0u; z.w = 0u;
        for (int e = tid; e < 50; e += 256)
            *(uint4*)&a1o[((size_t)n * 514) * 400 + e * 8] = z;
    }
    if (t0 == 480) {
        uint4 z; z.x = 0u; z.y = 0u; z.z = 0u; z.w = 0u;
        for (int e = tid; e < 50; e += 256)
            *(uint4*)&a1o[((size_t)n * 514 + 513) * 400 + e * 8] = z;
    }

    // --- zero Xt pad cols once (v = 25..31 per t; full 128B rows) ---
    {
        uint4 z; z.x = 0u; z.y = 0u; z.z = 0u; z.w = 0u;
        for (int e = tid; e < 448; e += 256) {
            const int pc = e >> 3, ch = e & 7;
            const int tl = pc / 7, pv = pc - tl * 7;
            const int col = tl * 32 + 25 + pv;
            *(uint4*)(XtB + col * 128 + ch * 16) = z;
        }
    }

    auto epilogue = [&](int tbp) {
        for (int e = tid; e < 2048; e += 256) {
            const int cc  = e >> 5;
            const int rem = e & 31;
            const int tl  = rem >> 2, v0 = (rem & 3) << 3;
            const int o   = (cc < 48) ? cc + 32 : cc - 32;
            uint4 pk = *(const uint4*)&Csh[o * 264 + tl * 32 + v0];
            *(uint4*)&hcn[(((size_t)n * 64 + cc) * 512 + (tbp + tl)) * 32 + v0] = pk;
        }
        for (int e = tid; e < 400; e += 256) {
            const int tv = e >> 1, h = (e & 1) << 3;
            const int tl = (tv * 41) >> 10;
            const int v  = tv - tl * 25;
            const int cb = tl * 32 + v;
            u16 a[8];
            #pragma unroll
            for (int k = 0; k < 8; ++k) a[k] = Csh[(h + k) * 264 + cb];
            uint4 pk;
            pk.x = (u32)a[0] | ((u32)a[1] << 16);
            pk.y = (u32)a[2] | ((u32)a[3] << 16);
            pk.z = (u32)a[4] | ((u32)a[5] << 16);
            pk.w = (u32)a[6] | ((u32)a[7] << 16);
            *(uint4*)&a1o[(((size_t)n * 514 + (tbp + tl + 1)) * 25 + v) * 16 + h] = pk;
        }
    };

    for (int s = 0; s < 4; ++s) {
        const int tb = t0 + s * 8;

        if (s > 0) epilogue(tb - 8);
        for (int e = tid; e < 400; e += 256) {
            const int co = e / 50;
            const int tq = e - co * 50;
            const float* gp = x + (((size_t)n * 64 + co * 8) * 512 + tb) * 25 + tq * 4;
            float fl[32];
            #pragma unroll
            for (int i = 0; i < 8; ++i) {
                const float4 t4 = *(const float4*)(gp + (size_t)i * 12800);
                fl[i * 4 + 0] = t4.x; fl[i * 4 + 1] = t4.y;
                fl[i * 4 + 2] = t4.z; fl[i * 4 + 3] = t4.w;
            }
            #pragma unroll
            for (int j = 0; j < 4; ++j) {
                const int tv  = tq * 4 + j;
                const int tl  = (tv * 41) >> 10;
                const int col = tl * 32 + (tv - tl * 25);
                uint4 pk;
                pk.x = pack2(fl[0 * 4 + j], fl[1 * 4 + j]);
                pk.y = pack2(fl[2 * 4 + j], fl[3 * 4 + j]);
                pk.z = pack2(fl[4 * 4 + j], fl[5 * 4 + j]);
                pk.w = pack2(fl[6 * 4 + j], fl[7 * 4 + j]);
                *(uint4*)(XtB + col * 128 + ((co * 16) ^ ((col & 7) << 4))) = pk;
            }
        }
        __syncthreads();

        {
            f32x4 acc[4][5];
            #pragma unroll
            for (int a_ = 0; a_ < 4; ++a_)
                #pragma unroll
                for (int m_ = 0; m_ < 5; ++m_)
                    acc[a_][m_] = (f32x4){0.f, 0.f, 0.f, 0.f};

            #pragma unroll
            for (int nt4 = 0; nt4 < 4; ++nt4) {
                const int col = (wave * 4 + nt4) * 16 + r;
                const int swz = (col & 7) << 4;
                const char* rowp = (const char*)Xt + col * 128;
                const bf16x8 x0 = *(const bf16x8*)(rowp + ((q * 16) ^ swz));
                const bf16x8 x1 = *(const bf16x8*)(rowp + ((64 + q * 16) ^ swz));
                #pragma unroll
                for (int mt = 0; mt < 5; ++mt) {
                    acc[nt4][mt] = __builtin_amdgcn_mfma_f32_16x16x32_bf16(
                        x0, wfrag[mt][0], acc[nt4][mt], 0, 0, 0);
                    acc[nt4][mt] = __builtin_amdgcn_mfma_f32_16x16x32_bf16(
                        x1, wfrag[mt][1], acc[nt4][mt], 0, 0, 0);
                }
            }
            #pragma unroll
            for (int nt4 = 0; nt4 < 4; ++nt4) {
                const int colb = (wave * 4 + nt4) * 16 + q * 4;
                #pragma unroll
                for (int mt = 0; mt < 5; ++mt) {
                    const int o = mt * 16 + r;
                    const float bi = breg[mt];
                    uint2 pr;
                    pr.x = pack2(acc[nt4][mt][0] + bi, acc[nt4][mt][1] + bi);
                    pr.y = pack2(acc[nt4][mt][2] + bi, acc[nt4][mt][3] + bi);
                    *(uint2*)&Csh[o * 264 + colb] = pr;
                }
            }
        }
        __syncthreads();
    }
    epilogue(t0 + 24);
}

// ---------------------------------------------------------------------------
// k2a: MFMA Gram matrix. Block = (n, 32-t chunk), 4 waves split k.
// 2-buffer parallel cross-wave reduce (r14).
// ---------------------------------------------------------------------------
__global__ __launch_bounds__(256, 2) void k2a_mfma(
    const u16* __restrict__ a1o, float* __restrict__ Spart)
{
    __shared__ u16 U[80 * 136];        // 21,760 B (stride 136: 2-way banks)
    __shared__ float Sred[80 * 80];    // 25,600 B
    __shared__ float Sred2[80 * 80];   // 25,600 B  (total 72,960 -> 2 blk/CU)
    const int b   = blockIdx.x;
    const int n   = b >> 4;
    const int tc  = b & 15;
    const int t0  = tc * 32;
    const int tid = threadIdx.x;
    const int wave = tid >> 6, lane = tid & 63;
    const int q = lane >> 4, col = lane & 15;

    f32x4 acc[25];
    #pragma unroll
    for (int i = 0; i < 25; ++i) acc[i] = (f32x4){0.f, 0.f, 0.f, 0.f};

    for (int s = 0; s < 4; ++s) {
        __syncthreads();                               // prior reads done
        for (int e = tid; e < 1280; e += 256) {        // stage 8 t's
            int row = e >> 4, c8 = (e & 15) << 3;
            uint4 val; val.x = 0u; val.y = 0u; val.z = 0u; val.w = 0u;
            if (row < 75) {
                int i = row / 25, v = row - i * 25;
                int tl = c8 >> 4, o0 = c8 & 8;
                int tp = t0 + s * 8 + tl + i;          // padded t idx, 0..513
                val = *(const uint4*)&a1o[(((size_t)n * 514 + tp) * 25 + v) * 16 + o0];
            }
            *(uint4*)&U[row * 136 + c8] = val;
        }
        __syncthreads();

        const int k0 = wave * 32 + q * 8;
        bf16x8 fr[5];
        #pragma unroll
        for (int r = 0; r < 5; ++r)
            fr[r] = *(const bf16x8*)&U[(r * 16 + col) * 136 + k0];
        #pragma unroll
        for (int mt = 0; mt < 5; ++mt)
            #pragma unroll
            for (int nt = 0; nt < 5; ++nt)
                acc[mt * 5 + nt] = __builtin_amdgcn_mfma_f32_16x16x32_bf16(
                    fr[mt], fr[nt], acc[mt * 5 + nt], 0, 0, 0);
    }

    // parallel reduce: waves 0/1 write Sred/Sred2; waves 2/3 add into them.
    if (wave < 2) {
        float* S = (wave == 0) ? Sred : Sred2;
        #pragma unroll
        for (int mt = 0; mt < 5; ++mt)
            #pragma unroll
            for (int nt = 0; nt < 5; ++nt)
                #pragma unroll
                for (int reg = 0; reg < 4; ++reg)
                    S[(mt * 16 + q * 4 + reg) * 80 + nt * 16 + col] =
                        acc[mt * 5 + nt][reg];
    }
    __syncthreads();
    if (wave >= 2) {
        float* S = (wave == 2) ? Sred : Sred2;
        #pragma unroll
        for (int mt = 0; mt < 5; ++mt)
            #pragma unroll
            for (int nt = 0; nt < 5; ++nt)
                #pragma unroll
                for (int reg = 0; reg < 4; ++reg)
                    S[(mt * 16 + q * 4 + reg) * 80 + nt * 16 + col] +=
                        acc[mt * 5 + nt][reg];
    }
    __syncthreads();
    float* dst = &Spart[(size_t)(n * 16 + tc) * 6400];
    for (int e = tid; e < 6400; e += 256) dst[e] = Sred[e] + Sred2[e];
}

// ---------------------------------------------------------------------------
// k2b: grid = (32 n x 5 w2-groups). Sum 16 partials, /75, column softmax
// over w1 with 16-lane shuffle trees; write BtT[n][80][96] = att^T.
// ---------------------------------------------------------------------------
__global__ __launch_bounds__(256) void k2b_softmax(
    const float* __restrict__ Spart, u16* __restrict__ BtT)
{
    __shared__ float S2[75][17];                  // [w1][w2l], pad to 17
    const int b = blockIdx.x;
    const int n = b / 5, w2g = b - n * 5;
    const int w2base = w2g * 16;
    const int tid = threadIdx.x;

    // phase 1: ks-reduction, 1200 elems
    for (int e = tid; e < 1200; e += 256) {
        const int w1 = e >> 4, w2l = e & 15;
        const float* sp = &Spart[(size_t)(n * 16) * 6400 + w1 * 80 + w2base + w2l];
        float s = 0.f;
        #pragma unroll
        for (int ks = 0; ks < 16; ++ks) s += sp[(size_t)ks * 6400];
        S2[w1][w2l] = s * (1.0f / 75.0f);
    }
    __syncthreads();

    // phase 2: softmax over w1, 16 lanes per column (cols are lane-contiguous)
    const int w2l = tid >> 4, j = tid & 15;
    float m = -1e30f;
    for (int w1 = j; w1 < 75; w1 += 16) m = fmaxf(m, S2[w1][w2l]);
    #pragma unroll
    for (int off = 8; off; off >>= 1) m = fmaxf(m, __shfl_xor(m, off, 16));
    float s = 0.f;
    for (int w1 = j; w1 < 75; w1 += 16) {
        const float e = __expf(S2[w1][w2l] - m);
        S2[w1][w2l] = e;
        s += e;
    }
    #pragma unroll
    for (int off = 8; off; off >>= 1) s += __shfl_xor(s, off, 16);
    const float r = 1.0f / s;
    for (int w1 = j; w1 < 75; w1 += 16) S2[w1][w2l] *= r;
    __syncthreads();

    // phase 3: store BtT rows w2base..w2base+15 (w2>=75 or v>=25 -> 0)
    for (int e = tid; e < 1536; e += 256) {
        const int wl = e / 96, k = e - wl * 96;
        const int i = k >> 5, v = k & 31;
        const int w2 = w2base + wl;
        const float val = (w2 < 75 && v < 25) ? S2[i * 25 + v][wl] : 0.f;
        BtT[((size_t)n * 80 + w2) * 96 + k] = f2b(val);
    }
}

// ---------------------------------------------------------------------------
// k34: fused graph contraction + conv3d + bias + BN + residual + relu.
// Block = (n, 8 t's), 2048 blocks, LDS 81,920 B exact -> 2 blocks/CU.
// ---------------------------------------------------------------------------
__global__ __launch_bounds__(256, 2) void k34_fused(
    const u16* __restrict__ hcn, const u16* __restrict__ BtA,
    const u16* __restrict__ BtT,
    const float* __restrict__ ow, const float* __restrict__ obias,
    const float* __restrict__ bg, const float* __restrict__ bb,
    const float* __restrict__ bm, const float* __restrict__ bv,
    const float* __restrict__ x, float* __restrict__ out)
{
    __shared__ __align__(16) char smem[81920];
    u16*   Bt   = (u16*)smem;                    // [80][392] = 62,720 B
    u16*   tile = (u16*)(smem + 62720);          // [8 tl][1200] = 19,200 B
    float* Csh  = (float*)smem;                  // [64 o][204] overlay (Bt dead)

    const int b    = blockIdx.x;
    const int n    = b >> 6;
    const int t0   = (b & 63) << 3;
    const int tid  = threadIdx.x;
    const int wave = tid >> 6, lane = tid & 63;
    const int q    = lane >> 4, c15 = lane & 15;

    // --- stage Bt (BtA cols 0..287, BtT cols 288..383) ---
    for (int e = tid; e < 3840; e += 256) {
        int row = e / 48, cs = e - row * 48;
        uint4 val;
        if (cs < 36) val = *(const uint4*)&BtA[row * 288 + cs * 8];
        else         val = *(const uint4*)&BtT[((size_t)n * 80 + row) * 96 + (cs - 36) * 8];
        *(uint4*)&Bt[row * 392 + cs * 8] = val;
    }
    __syncthreads();

    // --- k3-part: wave computes t-pair (t0 + 2*wave, +1) -> LDS tile ---
    {
        const int tp = t0 + 2 * wave;
        bf16x8 frag[4][4];                 // frag[g][s] = hcn @ tp-1+s
        #pragma unroll
        for (int g = 0; g < 4; ++g)
            #pragma unroll
            for (int s2 = 0; s2 < 4; ++s2) {
                const int t = tp - 1 + s2;
                frag[g][s2] = (t >= 0 && t < 512)
                    ? *(const bf16x8*)&hcn[(((size_t)n * 64 + g * 16 + c15) * 512 + t) * 32 + q * 8]
                    : (bf16x8)(short)0;
            }
        #pragma unroll 1
        for (int nt = 0; nt < 5; ++nt) {
            f32x4 acc0 = {0.f, 0.f, 0.f, 0.f};
            f32x4 acc1 = {0.f, 0.f, 0.f, 0.f};
            const u16* bp = &Bt[(nt * 16 + c15) * 392 + q * 8];
            #pragma unroll
            for (int g = 0; g < 4; ++g)
                #pragma unroll
                for (int i = 0; i < 3; ++i) {
                    bf16x8 bf = *(const bf16x8*)(bp + (g * 3 + i) * 32);
                    // swapped: A = Bt rows (w), B = hcn cols (c) -> D[w][c]
                    acc0 = __builtin_amdgcn_mfma_f32_16x16x32_bf16(bf, frag[g][i],     acc0, 0, 0, 0);
                    acc1 = __builtin_amdgcn_mfma_f32_16x16x32_bf16(bf, frag[g][i + 1], acc1, 0, 0, 0);
                }
            #pragma unroll
            for (int reg = 0; reg < 4; ++reg) {
                const int w = nt * 16 + q * 4 + reg;
                if (w < 75) {
                    const int ww = (w >= 50) ? 2 : ((w >= 25) ? 1 : 0);
                    const int v  = w - ww * 25;
                    const int off = (v * 3 + ww) * 16 + c15;
                    tile[(2 * wave)     * 1200 + off] = f2b(acc0[reg]);
                    tile[(2 * wave + 1) * 1200 + off] = f2b(acc1[reg]);
                }
            }
        }
    }

    // --- k4-part constants (registers; no LDS dependency) ---
    bf16x8 wfrag[4][2];
    #pragma unroll
    for (int mt = 0; mt < 4; ++mt) {
        const int o = mt * 16 + c15;
        #pragma unroll
        for (int ks = 0; ks < 2; ++ks) {
            bf16x8 f;
            #pragma unroll
            for (int j = 0; j < 8; ++j) {
                const int k = ks * 32 + q * 8 + j;
                const int cc = k & 15, ww = k >> 4;
                f[j] = (k < 48) ? (short)f2b(ow[o * 48 + cc * 3 + ww]) : (short)0;
            }
            wfrag[mt][ks] = f;
        }
    }
    float scl[4][4], shf2[4][4];
    #pragma unroll
    for (int mt = 0; mt < 4; ++mt)
        #pragma unroll
        for (int reg = 0; reg < 4; ++reg) {
            const int o = mt * 16 + q * 4 + reg;
            const float s = bg[o] * rsqrtf(bv[o] + 1e-5f);
            scl[mt][reg]  = s;
            shf2[mt][reg] = bb[o] + (obias[o] - bm[o]) * s;
        }
    __syncthreads();                              // tile complete, Bt dead

    // --- k4-part: MFMAs from tile; Csh writes overlay Bt region ---
    f32x4 acc[4][4];
    #pragma unroll
    for (int ct = 0; ct < 4; ++ct)
        #pragma unroll
        for (int mt = 0; mt < 4; ++mt)
            acc[ct][mt] = (f32x4){0.f, 0.f, 0.f, 0.f};

    const int wb = wave * 64;
    const int ww0 = q >> 1, cs2 = (q & 1) * 8;
    #pragma unroll
    for (int ct = 0; ct < 4; ++ct) {
        const int col = wb + ct * 16 + c15;
        const int tl = col >> 5, v = col & 31;
        const int vv = (v < 25) ? v : 0;          // clamp (garbage cols unused)
        const u16* trow = tile + tl * 1200;
        // ks=0: k = q*8+j -> ww = q>>1, c = (q&1)*8 + j  (contiguous 16B)
        const bf16x8 b0 = *(const bf16x8*)&trow[(vv * 3 + ww0) * 16 + cs2];
        // ks=1: k = 32+q*8+j -> ww = 2 for q<2 (valid); q>=2 is k>=48: wfrag=0
        const bf16x8 b1 = *(const bf16x8*)&trow[(vv * 3 + 2) * 16 + cs2];
        #pragma unroll
        for (int mt = 0; mt < 4; ++mt) {
            acc[ct][mt] = __builtin_amdgcn_mfma_f32_16x16x32_bf16(
                wfrag[mt][0], b0, acc[ct][mt], 0, 0, 0);
            acc[ct][mt] = __builtin_amdgcn_mfma_f32_16x16x32_bf16(
                wfrag[mt][1], b1, acc[ct][mt], 0, 0, 0);
        }
    }

    // acc (+BN) -> Csh[o][tl*25+v]; Csh overlays Bt (dead), not tile.
    #pragma unroll
    for (int ct = 0; ct < 4; ++ct) {
        const int col = wb + ct * 16 + c15;
        const int tl = col >> 5, v = col & 31;
        if (v < 25) {
            const int cc = tl * 25 + v;
            #pragma unroll
            for (int mt = 0; mt < 4; ++mt)
                #pragma unroll
                for (int reg = 0; reg < 4; ++reg) {
                    const int o = mt * 16 + q * 4 + reg;
                    Csh[o * 204 + cc] =
                        acc[ct][mt][reg] * scl[mt][reg] + shf2[mt][reg];
                }
        }
    }
    __syncthreads();

    // coalesced epilogue: float4 x-residual + relu + float4 out store.
    for (int e = tid; e < 3200; e += 256) {
        const int o = e / 50, jj = e - o * 50;
        const size_t gidx = (((size_t)n * 64 + o) * 512 + t0) * 25 + jj * 4;
        const float4 xv = *(const float4*)&x[gidx];
        const float* cp = &Csh[o * 204 + jj * 4];
        float4 yv;
        yv.x = fmaxf(cp[0] + xv.x, 0.f);
        yv.y = fmaxf(cp[1] + xv.y, 0.f);
        yv.z = fmaxf(cp[2] + xv.z, 0.f);
        yv.w = fmaxf(cp[3] + xv.w, 0.f);
        *(float4*)&out[gidx] = yv;
    }
}

// ---------------------------------------------------------------------------
extern "C" void kernel_launch(void* const* d_in, const int* in_sizes, int n_in,
                              void* d_out, int out_size, void* d_ws, size_t ws_size,
                              hipStream_t stream)
{
    const float* x  = (const float*)d_in[0];
    const float* A  = (const float*)d_in[1];
    const float* PA = (const float*)d_in[2];
    const float* wa = (const float*)d_in[3];
    const float* ba = (const float*)d_in[4];
    const float* wd = (const float*)d_in[5];
    const float* bd = (const float*)d_in[6];
    const float* wc = (const float*)d_in[7];
    const float* bc = (const float*)d_in[8];
    const float* ow = (const float*)d_in[9];
    const float* ob = (const float*)d_in[10];
    const float* bg = (const float*)d_in[11];
    const float* bb = (const float*)d_in[12];
    const float* bm = (const float*)d_in[13];
    const float* bv = (const float*)d_in[14];
    float* out = (float*)d_out;

    char* ws = (char*)d_ws;
    u16*   a1o   = (u16*)(ws);                           // 13,158,400 B
    u16*   hcn   = (u16*)(ws + 13158400);                // 67,108,864 B
    float* Spart = (float*)(ws + 80267264);              // 13,107,200 B (k2a->k2b)
    u16*   BtA   = (u16*)(ws + 130598912);               // 46,080 B
    u16*   BtT   = (u16*)(ws + 130644992);               // 491,520 B
    // total 131,136,512 B (sum12 region now unused — fused away)

    k0_bta    <<<90,   256, 0, stream>>>(A, PA, BtA);
    k1_conv80 <<<512,  256, 0, stream>>>(x, wa, ba, wd, bd, wc, bc, a1o, hcn);
    k2a_mfma  <<<512,  256, 0, stream>>>(a1o, Spart);
    k2b_softmax<<<160, 256, 0, stream>>>(Spart, BtT);
    k34_fused <<<2048, 256, 0, stream>>>(hcn, BtA, BtT, ow, ob, bg, bb, bm, bv, x, out);
}

// Round 12
// 377.508 us; speedup vs baseline: 1.2602x; 1.0084x over previous
//
#include <hip/hip_runtime.h>
#include <hip/hip_bf16.h>

// ============================================================================
// ConvTemporalGraphical — round 16: hcn layout transposed to [n][t][64cc][32v]
// (k34 frag loads become contiguous 1KB/wave instead of 16-line scatter) +
// k34 frag/const loads issued BEFORE the Bt barrier (latency hides under
// staging). k0/k2a/k2b unchanged; k1 epilogue re-indexed for the new layout.
//
//   k0: BtA[80w][288k] = Aeff^T bf16, K regions r=g*3+i, k=r*32+v (padded).
//   k1: MFMA 80-ch 1x1 conv; hcn stores now [n][t][cc][32] (4KB/t panels).
//   k2a: MFMA Gram, 2-buffer parallel cross-wave reduce.
//   k2b: 160 blocks (n x 5 w2-groups), shuffle-tree column softmax.
//   k34: fused graph contraction + conv3d + BN + residual + relu.
//        frag[g][s] loads: ((n*512+t)*64 + g*16+c15)*32 + q*8 — coalesced.
//
// ws: a1o 0..13,158,400 | hcn ..80,267,264 | Spart 80,267,264..93,374,464 |
//     BtA 130,598,912 | BtT 130,644,992
// ============================================================================

typedef unsigned short u16;
typedef unsigned int   u32;
typedef __attribute__((ext_vector_type(8))) short bf16x8;
typedef __attribute__((ext_vector_type(4))) float f32x4;

__device__ __forceinline__ float b2f(u32 u) {
    union { u32 i; float f; } x; x.i = (u & 0xffffu) << 16; return x.f;
}
__device__ __forceinline__ u16 f2b(float f) {
    union { float f; u32 i; } x; x.f = f;
    u32 i = x.i;
    return (u16)((i + 0x7fffu + ((i >> 16) & 1u)) >> 16);   // RNE
}
__device__ __forceinline__ u32 pack2(float a, float b) {
    return (u32)f2b(a) | ((u32)f2b(b) << 16);
}

// ---------------------------------------------------------------------------
// k0: BtA = Aeff^T with (g,i)-region K layout, zero-padded.
// ---------------------------------------------------------------------------
__global__ __launch_bounds__(256) void k0_bta(
    const float* __restrict__ A, const float* __restrict__ PA,
    u16* __restrict__ BtA)
{
    int e = blockIdx.x * 256 + threadIdx.x;
    if (e >= 80 * 288) return;
    int w = e / 288, k = e - w * 288;
    int r = k >> 5, v = k & 31, g = r / 3, i = r - g * 3;
    float val = 0.f;
    if (v < 25 && w < 75) {
        int idx = (g * 75 + i * 25 + v) * 75 + w;
        val = A[idx] + PA[idx];
    }
    BtA[e] = f2b(val);
}

// ---------------------------------------------------------------------------
// k1: MFMA 80-ch 1x1 conv. Block = (n, 32 t's), 256 thr (4 waves), 4 stages.
// hcn stores: [n][t][cc][32v] — 4KB contiguous per t-panel.
// ---------------------------------------------------------------------------
__global__ __launch_bounds__(256, 2) void k1_conv80(
    const float* __restrict__ x,
    const float* __restrict__ wa, const float* __restrict__ ba,
    const float* __restrict__ wd, const float* __restrict__ bd,
    const float* __restrict__ wc, const float* __restrict__ bc,
    u16* __restrict__ a1o, u16* __restrict__ hcn)
{
    __shared__ __align__(16) u16 Xt[256 * 64];    // 32,768 B, [col][c] swizzled
    __shared__ __align__(16) u16 Csh[80 * 264];   // 42,240 B, [o][col] stride 264
    char* XtB = (char*)Xt;

    const int b    = blockIdx.x;
    const int n    = b >> 4;
    const int t0   = (b & 15) << 5;               // 32 t's per block
    const int tid  = threadIdx.x;
    const int wave = tid >> 6, lane = tid & 63;
    const int q    = lane >> 4, r = lane & 15;

    // --- per-block preload: W fragments (B-operand layout) + bias ---
    bf16x8 wfrag[5][2];
    float  breg[5];
    #pragma unroll
    for (int mt = 0; mt < 5; ++mt) {
        const int o = mt * 16 + r;
        const float* src = (o < 16) ? (wa + o * 64)
                         : (o < 32) ? (wd + (o - 16) * 64)
                                    : (wc + (o - 32) * 64);
        breg[mt] = (o < 16) ? ba[o] : (o < 32) ? bd[o - 16] : bc[o - 32];
        #pragma unroll
        for (int ks = 0; ks < 2; ++ks) {
            bf16x8 f;
            #pragma unroll
            for (int j = 0; j < 8; ++j)
                f[j] = (short)f2b(src[ks * 32 + q * 8 + j]);
            wfrag[mt][ks] = f;
        }
    }

    // --- a1o t-pad rows (ws is poisoned each launch) ---
    if (t0 == 0) {
        uint4 z; z.x = 0u; z.y = 0u; z.z = 0u; z.w = 0u;
        for (int e = tid; e < 50; e += 256)
            *(uint4*)&a1o[((size_t)n * 514) * 400 + e * 8] = z;
    }
    if (t0 == 480) {
        uint4 z; z.x = 0u; z.y = 0u; z.z = 0u; z.w = 0u;
        for (int e = tid; e < 50; e += 256)
            *(uint4*)&a1o[((size_t)n * 514 + 513) * 400 + e * 8] = z;
    }

    // --- zero Xt pad cols once (v = 25..31 per t; full 128B rows) ---
    {
        uint4 z; z.x = 0u; z.y = 0u; z.z = 0u; z.w = 0u;
        for (int e = tid; e < 448; e += 256) {
            const int pc = e >> 3, ch = e & 7;
            const int tl = pc / 7, pv = pc - tl * 7;
            const int col = tl * 32 + 25 + pv;
            *(uint4*)(XtB + col * 128 + ch * 16) = z;
        }
    }

    auto epilogue = [&](int tbp) {
        // hcn: [n][t][cc][32v]; e -> (tl, cc, v0): contiguous 4KB per tl.
        for (int e = tid; e < 2048; e += 256) {
            const int tl  = e >> 8;
            const int rem = e & 255;
            const int cc  = rem >> 2, v0 = (rem & 3) << 3;
            const int o   = (cc < 48) ? cc + 32 : cc - 32;
            uint4 pk = *(const uint4*)&Csh[o * 264 + tl * 32 + v0];
            *(uint4*)&hcn[(((size_t)n * 512 + (tbp + tl)) * 64 + cc) * 32 + v0] = pk;
        }
        for (int e = tid; e < 400; e += 256) {
            const int tv = e >> 1, h = (e & 1) << 3;
            const int tl = (tv * 41) >> 10;
            const int v  = tv - tl * 25;
            const int cb = tl * 32 + v;
            u16 a[8];
            #pragma unroll
            for (int k = 0; k < 8; ++k) a[k] = Csh[(h + k) * 264 + cb];
            uint4 pk;
            pk.x = (u32)a[0] | ((u32)a[1] << 16);
            pk.y = (u32)a[2] | ((u32)a[3] << 16);
            pk.z = (u32)a[4] | ((u32)a[5] << 16);
            pk.w = (u32)a[6] | ((u32)a[7] << 16);
            *(uint4*)&a1o[(((size_t)n * 514 + (tbp + tl + 1)) * 25 + v) * 16 + h] = pk;
        }
    };

    for (int s = 0; s < 4; ++s) {
        const int tb = t0 + s * 8;

        if (s > 0) epilogue(tb - 8);
        for (int e = tid; e < 400; e += 256) {
            const int co = e / 50;
            const int tq = e - co * 50;
            const float* gp = x + (((size_t)n * 64 + co * 8) * 512 + tb) * 25 + tq * 4;
            float fl[32];
            #pragma unroll
            for (int i = 0; i < 8; ++i) {
                const float4 t4 = *(const float4*)(gp + (size_t)i * 12800);
                fl[i * 4 + 0] = t4.x; fl[i * 4 + 1] = t4.y;
                fl[i * 4 + 2] = t4.z; fl[i * 4 + 3] = t4.w;
            }
            #pragma unroll
            for (int j = 0; j < 4; ++j) {
                const int tv  = tq * 4 + j;
                const int tl  = (tv * 41) >> 10;
                const int col = tl * 32 + (tv - tl * 25);
                uint4 pk;
                pk.x = pack2(fl[0 * 4 + j], fl[1 * 4 + j]);
                pk.y = pack2(fl[2 * 4 + j], fl[3 * 4 + j]);
                pk.z = pack2(fl[4 * 4 + j], fl[5 * 4 + j]);
                pk.w = pack2(fl[6 * 4 + j], fl[7 * 4 + j]);
                *(uint4*)(XtB + col * 128 + ((co * 16) ^ ((col & 7) << 4))) = pk;
            }
        }
        __syncthreads();

        {
            f32x4 acc[4][5];
            #pragma unroll
            for (int a_ = 0; a_ < 4; ++a_)
                #pragma unroll
                for (int m_ = 0; m_ < 5; ++m_)
                    acc[a_][m_] = (f32x4){0.f, 0.f, 0.f, 0.f};

            #pragma unroll
            for (int nt4 = 0; nt4 < 4; ++nt4) {
                const int col = (wave * 4 + nt4) * 16 + r;
                const int swz = (col & 7) << 4;
                const char* rowp = (const char*)Xt + col * 128;
                const bf16x8 x0 = *(const bf16x8*)(rowp + ((q * 16) ^ swz));
                const bf16x8 x1 = *(const bf16x8*)(rowp + ((64 + q * 16) ^ swz));
                #pragma unroll
                for (int mt = 0; mt < 5; ++mt) {
                    acc[nt4][mt] = __builtin_amdgcn_mfma_f32_16x16x32_bf16(
                        x0, wfrag[mt][0], acc[nt4][mt], 0, 0, 0);
                    acc[nt4][mt] = __builtin_amdgcn_mfma_f32_16x16x32_bf16(
                        x1, wfrag[mt][1], acc[nt4][mt], 0, 0, 0);
                }
            }
            #pragma unroll
            for (int nt4 = 0; nt4 < 4; ++nt4) {
                const int colb = (wave * 4 + nt4) * 16 + q * 4;
                #pragma unroll
                for (int mt = 0; mt < 5; ++mt) {
                    const int o = mt * 16 + r;
                    const float bi = breg[mt];
                    uint2 pr;
                    pr.x = pack2(acc[nt4][mt][0] + bi, acc[nt4][mt][1] + bi);
                    pr.y = pack2(acc[nt4][mt][2] + bi, acc[nt4][mt][3] + bi);
                    *(uint2*)&Csh[o * 264 + colb] = pr;
                }
            }
        }
        __syncthreads();
    }
    epilogue(t0 + 24);
}

// ---------------------------------------------------------------------------
// k2a: MFMA Gram matrix. Block = (n, 32-t chunk), 4 waves split k.
// 2-buffer parallel cross-wave reduce (r14).
// ---------------------------------------------------------------------------
__global__ __launch_bounds__(256, 2) void k2a_mfma(
    const u16* __restrict__ a1o, float* __restrict__ Spart)
{
    __shared__ u16 U[80 * 136];        // 21,760 B (stride 136: 2-way banks)
    __shared__ float Sred[80 * 80];    // 25,600 B
    __shared__ float Sred2[80 * 80];   // 25,600 B  (total 72,960 -> 2 blk/CU)
    const int b   = blockIdx.x;
    const int n   = b >> 4;
    const int tc  = b & 15;
    const int t0  = tc * 32;
    const int tid = threadIdx.x;
    const int wave = tid >> 6, lane = tid & 63;
    const int q = lane >> 4, col = lane & 15;

    f32x4 acc[25];
    #pragma unroll
    for (int i = 0; i < 25; ++i) acc[i] = (f32x4){0.f, 0.f, 0.f, 0.f};

    for (int s = 0; s < 4; ++s) {
        __syncthreads();                               // prior reads done
        for (int e = tid; e < 1280; e += 256) {        // stage 8 t's
            int row = e >> 4, c8 = (e & 15) << 3;
            uint4 val; val.x = 0u; val.y = 0u; val.z = 0u; val.w = 0u;
            if (row < 75) {
                int i = row / 25, v = row - i * 25;
                int tl = c8 >> 4, o0 = c8 & 8;
                int tp = t0 + s * 8 + tl + i;          // padded t idx, 0..513
                val = *(const uint4*)&a1o[(((size_t)n * 514 + tp) * 25 + v) * 16 + o0];
            }
            *(uint4*)&U[row * 136 + c8] = val;
        }
        __syncthreads();

        const int k0 = wave * 32 + q * 8;
        bf16x8 fr[5];
        #pragma unroll
        for (int r = 0; r < 5; ++r)
            fr[r] = *(const bf16x8*)&U[(r * 16 + col) * 136 + k0];
        #pragma unroll
        for (int mt = 0; mt < 5; ++mt)
            #pragma unroll
            for (int nt = 0; nt < 5; ++nt)
                acc[mt * 5 + nt] = __builtin_amdgcn_mfma_f32_16x16x32_bf16(
                    fr[mt], fr[nt], acc[mt * 5 + nt], 0, 0, 0);
    }

    // parallel reduce: waves 0/1 write Sred/Sred2; waves 2/3 add into them.
    if (wave < 2) {
        float* S = (wave == 0) ? Sred : Sred2;
        #pragma unroll
        for (int mt = 0; mt < 5; ++mt)
            #pragma unroll
            for (int nt = 0; nt < 5; ++nt)
                #pragma unroll
                for (int reg = 0; reg < 4; ++reg)
                    S[(mt * 16 + q * 4 + reg) * 80 + nt * 16 + col] =
                        acc[mt * 5 + nt][reg];
    }
    __syncthreads();
    if (wave >= 2) {
        float* S = (wave == 2) ? Sred : Sred2;
        #pragma unroll
        for (int mt = 0; mt < 5; ++mt)
            #pragma unroll
            for (int nt = 0; nt < 5; ++nt)
                #pragma unroll
                for (int reg = 0; reg < 4; ++reg)
                    S[(mt * 16 + q * 4 + reg) * 80 + nt * 16 + col] +=
                        acc[mt * 5 + nt][reg];
    }
    __syncthreads();
    float* dst = &Spart[(size_t)(n * 16 + tc) * 6400];
    for (int e = tid; e < 6400; e += 256) dst[e] = Sred[e] + Sred2[e];
}

// ---------------------------------------------------------------------------
// k2b: grid = (32 n x 5 w2-groups). Sum 16 partials, /75, column softmax
// over w1 with 16-lane shuffle trees; write BtT[n][80][96] = att^T.
// ---------------------------------------------------------------------------
__global__ __launch_bounds__(256) void k2b_softmax(
    const float* __restrict__ Spart, u16* __restrict__ BtT)
{
    __shared__ float S2[75][17];                  // [w1][w2l], pad to 17
    const int b = blockIdx.x;
    const int n = b / 5, w2g = b - n * 5;
    const int w2base = w2g * 16;
    const int tid = threadIdx.x;

    // phase 1: ks-reduction, 1200 elems
    for (int e = tid; e < 1200; e += 256) {
        const int w1 = e >> 4, w2l = e & 15;
        const float* sp = &Spart[(size_t)(n * 16) * 6400 + w1 * 80 + w2base + w2l];
        float s = 0.f;
        #pragma unroll
        for (int ks = 0; ks < 16; ++ks) s += sp[(size_t)ks * 6400];
        S2[w1][w2l] = s * (1.0f / 75.0f);
    }
    __syncthreads();

    // phase 2: softmax over w1, 16 lanes per column (cols are lane-contiguous)
    const int w2l = tid >> 4, j = tid & 15;
    float m = -1e30f;
    for (int w1 = j; w1 < 75; w1 += 16) m = fmaxf(m, S2[w1][w2l]);
    #pragma unroll
    for (int off = 8; off; off >>= 1) m = fmaxf(m, __shfl_xor(m, off, 16));
    float s = 0.f;
    for (int w1 = j; w1 < 75; w1 += 16) {
        const float e = __expf(S2[w1][w2l] - m);
        S2[w1][w2l] = e;
        s += e;
    }
    #pragma unroll
    for (int off = 8; off; off >>= 1) s += __shfl_xor(s, off, 16);
    const float r = 1.0f / s;
    for (int w1 = j; w1 < 75; w1 += 16) S2[w1][w2l] *= r;
    __syncthreads();

    // phase 3: store BtT rows w2base..w2base+15 (w2>=75 or v>=25 -> 0)
    for (int e = tid; e < 1536; e += 256) {
        const int wl = e / 96, k = e - wl * 96;
        const int i = k >> 5, v = k & 31;
        const int w2 = w2base + wl;
        const float val = (w2 < 75 && v < 25) ? S2[i * 25 + v][wl] : 0.f;
        BtT[((size_t)n * 80 + w2) * 96 + k] = f2b(val);
    }
}

// ---------------------------------------------------------------------------
// k34: fused graph contraction + conv3d + bias + BN + residual + relu.
// Block = (n, 8 t's), 2048 blocks, LDS 81,920 B exact -> 2 blocks/CU.
// hcn reads coalesced ([n][t][cc][32v]); frag/const loads issued before the
// Bt barrier so HBM latency hides under staging.
// ---------------------------------------------------------------------------
__global__ __launch_bounds__(256, 2) void k34_fused(
    const u16* __restrict__ hcn, const u16* __restrict__ BtA,
    const u16* __restrict__ BtT,
    const float* __restrict__ ow, const float* __restrict__ obias,
    const float* __restrict__ bg, const float* __restrict__ bb,
    const float* __restrict__ bm, const float* __restrict__ bv,
    const float* __restrict__ x, float* __restrict__ out)
{
    __shared__ __align__(16) char smem[81920];
    u16*   Bt   = (u16*)smem;                    // [80][392] = 62,720 B
    u16*   tile = (u16*)(smem + 62720);          // [8 tl][1200] = 19,200 B
    float* Csh  = (float*)smem;                  // [64 o][204] overlay (Bt dead)

    const int b    = blockIdx.x;
    const int n    = b >> 6;
    const int t0   = (b & 63) << 3;
    const int tid  = threadIdx.x;
    const int wave = tid >> 6, lane = tid & 63;
    const int q    = lane >> 4, c15 = lane & 15;

    // --- stage Bt (issue first; barrier later) ---
    for (int e = tid; e < 3840; e += 256) {
        int row = e / 48, cs = e - row * 48;
        uint4 val;
        if (cs < 36) val = *(const uint4*)&BtA[row * 288 + cs * 8];
        else         val = *(const uint4*)&BtT[((size_t)n * 80 + row) * 96 + (cs - 36) * 8];
        *(uint4*)&Bt[row * 392 + cs * 8] = val;
    }

    // --- prefetch hcn frags (coalesced: 1KB per (g,t) per wave) ---
    const int tp = t0 + 2 * wave;
    bf16x8 frag[4][4];                 // frag[g][s] = hcn @ tp-1+s
    #pragma unroll
    for (int g = 0; g < 4; ++g)
        #pragma unroll
        for (int s2 = 0; s2 < 4; ++s2) {
            const int t = tp - 1 + s2;
            frag[g][s2] = (t >= 0 && t < 512)
                ? *(const bf16x8*)&hcn[(((size_t)n * 512 + t) * 64 + g * 16 + c15) * 32 + q * 8]
                : (bf16x8)(short)0;
        }

    // --- k4-part constants (registers; no LDS dependency) ---
    bf16x8 wfrag[4][2];
    #pragma unroll
    for (int mt = 0; mt < 4; ++mt) {
        const int o = mt * 16 + c15;
        #pragma unroll
        for (int ks = 0; ks < 2; ++ks) {
            bf16x8 f;
            #pragma unroll
            for (int j = 0; j < 8; ++j) {
                const int k = ks * 32 + q * 8 + j;
                const int cc = k & 15, ww = k >> 4;
                f[j] = (k < 48) ? (short)f2b(ow[o * 48 + cc * 3 + ww]) : (short)0;
            }
            wfrag[mt][ks] = f;
        }
    }
    float scl[4][4], shf2[4][4];
    #pragma unroll
    for (int mt = 0; mt < 4; ++mt)
        #pragma unroll
        for (int reg = 0; reg < 4; ++reg) {
            const int o = mt * 16 + q * 4 + reg;
            const float s = bg[o] * rsqrtf(bv[o] + 1e-5f);
            scl[mt][reg]  = s;
            shf2[mt][reg] = bb[o] + (obias[o] - bm[o]) * s;
        }
    __syncthreads();                              // Bt staged

    // --- k3-part: wave computes t-pair (t0 + 2*wave, +1) -> LDS tile ---
    #pragma unroll 1
    for (int nt = 0; nt < 5; ++nt) {
        f32x4 acc0 = {0.f, 0.f, 0.f, 0.f};
        f32x4 acc1 = {0.f, 0.f, 0.f, 0.f};
        const u16* bp = &Bt[(nt * 16 + c15) * 392 + q * 8];
        #pragma unroll
        for (int g = 0; g < 4; ++g)
            #pragma unroll
            for (int i = 0; i < 3; ++i) {
                bf16x8 bf = *(const bf16x8*)(bp + (g * 3 + i) * 32);
                // swapped: A = Bt rows (w), B = hcn cols (c) -> D[w][c]
                acc0 = __builtin_amdgcn_mfma_f32_16x16x32_bf16(bf, frag[g][i],     acc0, 0, 0, 0);
                acc1 = __builtin_amdgcn_mfma_f32_16x16x32_bf16(bf, frag[g][i + 1], acc1, 0, 0, 0);
            }
        #pragma unroll
        for (int reg = 0; reg < 4; ++reg) {
            const int w = nt * 16 + q * 4 + reg;
            if (w < 75) {
                const int ww = (w >= 50) ? 2 : ((w >= 25) ? 1 : 0);
                const int v  = w - ww * 25;
                const int off = (v * 3 + ww) * 16 + c15;
                tile[(2 * wave)     * 1200 + off] = f2b(acc0[reg]);
                tile[(2 * wave + 1) * 1200 + off] = f2b(acc1[reg]);
            }
        }
    }
    __syncthreads();                              // tile complete, Bt dead

    // --- k4-part: MFMAs from tile; Csh writes overlay Bt region ---
    f32x4 acc[4][4];
    #pragma unroll
    for (int ct = 0; ct < 4; ++ct)
        #pragma unroll
        for (int mt = 0; mt < 4; ++mt)
            acc[ct][mt] = (f32x4){0.f, 0.f, 0.f, 0.f};

    const int wb = wave * 64;
    const int ww0 = q >> 1, cs2 = (q & 1) * 8;
    #pragma unroll
    for (int ct = 0; ct < 4; ++ct) {
        const int col = wb + ct * 16 + c15;
        const int tl = col >> 5, v = col & 31;
        const int vv = (v < 25) ? v : 0;          // clamp (garbage cols unused)
        const u16* trow = tile + tl * 1200;
        // ks=0: k = q*8+j -> ww = q>>1, c = (q&1)*8 + j  (contiguous 16B)
        const bf16x8 b0 = *(const bf16x8*)&trow[(vv * 3 + ww0) * 16 + cs2];
        // ks=1: k = 32+q*8+j -> ww = 2 for q<2 (valid); q>=2 is k>=48: wfrag=0
        const bf16x8 b1 = *(const bf16x8*)&trow[(vv * 3 + 2) * 16 + cs2];
        #pragma unroll
        for (int mt = 0; mt < 4; ++mt) {
            acc[ct][mt] = __builtin_amdgcn_mfma_f32_16x16x32_bf16(
                wfrag[mt][0], b0, acc[ct][mt], 0, 0, 0);
            acc[ct][mt] = __builtin_amdgcn_mfma_f32_16x16x32_bf16(
                wfrag[mt][1], b1, acc[ct][mt], 0, 0, 0);
        }
    }

    // acc (+BN) -> Csh[o][tl*25+v]; Csh overlays Bt (dead), not tile.
    #pragma unroll
    for (int ct = 0; ct < 4; ++ct) {
        const int col = wb + ct * 16 + c15;
        const int tl = col >> 5, v = col & 31;
        if (v < 25) {
            const int cc = tl * 25 + v;
            #pragma unroll
            for (int mt = 0; mt < 4; ++mt)
                #pragma unroll
                for (int reg = 0; reg < 4; ++reg) {
                    const int o = mt * 16 + q * 4 + reg;
                    Csh[o * 204 + cc] =
                        acc[ct][mt][reg] * scl[mt][reg] + shf2[mt][reg];
                }
        }
    }
    __syncthreads();

    // coalesced epilogue: float4 x-residual + relu + float4 out store.
    for (int e = tid; e < 3200; e += 256) {
        const int o = e / 50, jj = e - o * 50;
        const size_t gidx = (((size_t)n * 64 + o) * 512 + t0) * 25 + jj * 4;
        const float4 xv = *(const float4*)&x[gidx];
        const float* cp = &Csh[o * 204 + jj * 4];
        float4 yv;
        yv.x = fmaxf(cp[0] + xv.x, 0.f);
        yv.y = fmaxf(cp[1] + xv.y, 0.f);
        yv.z = fmaxf(cp[2] + xv.z, 0.f);
        yv.w = fmaxf(cp[3] + xv.w, 0.f);
        *(float4*)&out[gidx] = yv;
    }
}

// ---------------------------------------------------------------------------
extern "C" void kernel_launch(void* const* d_in, const int* in_sizes, int n_in,
                              void* d_out, int out_size, void* d_ws, size_t ws_size,
                              hipStream_t stream)
{
    const float* x  = (const float*)d_in[0];
    const float* A  = (const float*)d_in[1];
    const float* PA = (const float*)d_in[2];
    const float* wa = (const float*)d_in[3];
    const float* ba = (const float*)d_in[4];
    const float* wd = (const float*)d_in[5];
    const float* bd = (const float*)d_in[6];
    const float* wc = (const float*)d_in[7];
    const float* bc = (const float*)d_in[8];
    const float* ow = (const float*)d_in[9];
    const float* ob = (const float*)d_in[10];
    const float* bg = (const float*)d_in[11];
    const float* bb = (const float*)d_in[12];
    const float* bm = (const float*)d_in[13];
    const float* bv = (const float*)d_in[14];
    float* out = (float*)d_out;

    char* ws = (char*)d_ws;
    u16*   a1o   = (u16*)(ws);                           // 13,158,400 B
    u16*   hcn   = (u16*)(ws + 13158400);                // 67,108,864 B
    float* Spart = (float*)(ws + 80267264);              // 13,107,200 B (k2a->k2b)
    u16*   BtA   = (u16*)(ws + 130598912);               // 46,080 B
    u16*   BtT   = (u16*)(ws + 130644992);               // 491,520 B
    // total 131,136,512 B (sum12 region unused — fused away)

    k0_bta    <<<90,   256, 0, stream>>>(A, PA, BtA);
    k1_conv80 <<<512,  256, 0, stream>>>(x, wa, ba, wd, bd, wc, bc, a1o, hcn);
    k2a_mfma  <<<512,  256, 0, stream>>>(a1o, Spart);
    k2b_softmax<<<160, 256, 0, stream>>>(Spart, BtT);
    k34_fused <<<2048, 256, 0, stream>>>(hcn, BtA, BtT, ow, ob, bg, bb, bm, bv, x, out);
}